// Round 13
// baseline (912.218 us; speedup 1.0000x reference)
//
#include <hip/hip_runtime.h>
#include <hip/hip_bf16.h>
#include <math.h>

typedef __hip_bfloat16 bf16;
typedef __attribute__((ext_vector_type(8))) short short8x;
typedef __attribute__((ext_vector_type(4))) float f32x4;

// ---- problem constants ----
static constexpr int cB   = 2;
static constexpr int cL   = 1024;
static constexpr int cLE  = 1024;
static constexpr int cNM  = 80;
static constexpr int cDM  = 512;
static constexpr int cLAYERS = 4;
static constexpr int cDS  = 16;
static constexpr int cKC  = 4;     // conv taps
static constexpr int cH   = 4;     // heads
static constexpr int cDI  = 1024;  // EXP*DM
static constexpr int cDTR = 32;
static constexpr int cHD  = 128;   // head dim

static constexpr int cNCH = 64;    // scan chunks
static constexpr int cCHL = cL / cNCH;  // 16 steps per chunk
static constexpr int cSPL = 4;     // flash KV splits

#define GLL16(g, l) __builtin_amdgcn_global_load_lds( \
    (const __attribute__((address_space(1))) void*)(g), \
    (__attribute__((address_space(3))) void*)(l), 16, 0, 0)

// =====================================================================
// bf16 MFMA GEMM, BMxBN tile, 4 waves (2x2), K-step 32.
// =====================================================================
template<int ACT, int BM, int BN>
__global__ __launch_bounds__(256)
void bgemm_kernel(const bf16* __restrict__ A, const bf16* __restrict__ W,
                  const float* __restrict__ bias, const float* __restrict__ addv,
                  float* __restrict__ Cf, bf16* __restrict__ Cb,
                  int M, int N, int Kd, int lda, int ldw, int ldcf, int ldcb, int ldadd,
                  int bdiv, long sA1, long sA2, long sW1, long sW2,
                  long sCf1, long sCf2, long sCb1, long sCb2, long sBias)
{
    constexpr int RM = BM / 32;
    constexpr int RN = BN / 32;
    const int z = blockIdx.z;
    const int i1 = z / bdiv, i2 = z % bdiv;
    A += i1 * sA1 + i2 * sA2;
    W += i1 * sW1 + i2 * sW2;
    if (bias) bias += i1 * sBias;

    const int bm = blockIdx.y * BM;
    const int bn = blockIdx.x * BN;
    const int tid = threadIdx.x;
    const int lane = tid & 63;
    const int wid = tid >> 6;
    const int wr = wid >> 1, wc = wid & 1;

    __shared__ bf16 As[BM * 32];
    __shared__ bf16 Bs[BN * 32];

    f32x4 acc[RM][RN] = {};

    const int r_in = lane >> 2;
    const int kb   = (lane & 3) * 8;
    const int hi   = lane >> 4;
    const int rc   = lane & 15;

    for (int k0 = 0; k0 < Kd; k0 += 32) {
#pragma unroll
        for (int iss = 0; iss < BM / 64; iss++) {
            const int row = wid * (BM / 4) + iss * 16 + r_in;
            int gm = bm + row; if (gm >= M) gm = M - 1;
            const bf16* ga = A + (long)gm * lda + k0 + kb;
            GLL16(ga, As + (wid * (BM / 4) + iss * 16) * 32);
        }
#pragma unroll
        for (int iss = 0; iss < BN / 64; iss++) {
            const int row = wid * (BN / 4) + iss * 16 + r_in;
            int gn = bn + row; if (gn >= N) gn = N - 1;
            const bf16* gb = W + (long)gn * ldw + k0 + kb;
            GLL16(gb, Bs + (wid * (BN / 4) + iss * 16) * 32);
        }
        asm volatile("s_waitcnt vmcnt(0)" ::: "memory");
        __syncthreads();

        short8x af[RM], bfv[RN];
#pragma unroll
        for (int i = 0; i < RM; i++)
            af[i] = *(const short8x*)(As + (wr * (BM / 2) + i * 16 + rc) * 32 + hi * 8);
#pragma unroll
        for (int j = 0; j < RN; j++)
            bfv[j] = *(const short8x*)(Bs + (wc * (BN / 2) + j * 16 + rc) * 32 + hi * 8);
#pragma unroll
        for (int i = 0; i < RM; i++)
#pragma unroll
            for (int j = 0; j < RN; j++)
                acc[i][j] = __builtin_amdgcn_mfma_f32_16x16x32_bf16(af[i], bfv[j], acc[i][j], 0, 0, 0);
        __syncthreads();
    }

    const long cfo = i1 * sCf1 + i2 * sCf2;
    const long cbo = i1 * sCb1 + i2 * sCb2;
#pragma unroll
    for (int i = 0; i < RM; i++) {
#pragma unroll
        for (int r = 0; r < 4; r++) {
            const int gm = bm + wr * (BM / 2) + i * 16 + hi * 4 + r;
            if (gm >= M) continue;
#pragma unroll
            for (int j = 0; j < RN; j++) {
                const int gn = bn + wc * (BN / 2) + j * 16 + rc;
                if (gn >= N) continue;
                float v = acc[i][j][r];
                if (bias) v += bias[gn];
                if (ACT == 1) v = (v > 20.f) ? v : log1pf(__expf(v));
                if (addv) v += addv[cfo + (long)gm * ldadd + gn];
                if (Cf) Cf[cfo + (long)gm * ldcf + gn] = v;
                if (Cb) Cb[cbo + (long)gm * ldcb + gn] = __float2bfloat16(v);
            }
        }
    }
}

static inline void bgemm(int ACT, int BM, int BN, const bf16* A, const bf16* W, const float* bias,
                         const float* addv, float* Cf, bf16* Cb,
                         int M, int N, int Kd, int lda, int ldw, int ldcf, int ldcb, int ldadd,
                         int nz, int bdiv, long sA1, long sA2, long sW1, long sW2,
                         long sCf1, long sCf2, long sCb1, long sCb2, long sBias, hipStream_t s)
{
    dim3 g((N + BN - 1) / BN, (M + BM - 1) / BM, nz), b(256);
#define BG_ARGS A, W, bias, addv, Cf, Cb, M, N, Kd, lda, ldw, ldcf, ldcb, ldadd, \
                bdiv, sA1, sA2, sW1, sW2, sCf1, sCf2, sCb1, sCb2, sBias
    if (BM == 128) {
        if (ACT == 1) bgemm_kernel<1, 128, 128><<<g, b, 0, s>>>(BG_ARGS);
        else          bgemm_kernel<0, 128, 128><<<g, b, 0, s>>>(BG_ARGS);
    } else if (BN == 128) {
        if (ACT == 1) bgemm_kernel<1, 64, 128><<<g, b, 0, s>>>(BG_ARGS);
        else          bgemm_kernel<0, 64, 128><<<g, b, 0, s>>>(BG_ARGS);
    } else {
        bgemm_kernel<0, 64, 64><<<g, b, 0, s>>>(BG_ARGS);
    }
#undef BG_ARGS
}

static inline void bgemm_plain(int ACT, int BM, int BN, const bf16* A, const bf16* W,
                               const float* bias, const float* addv, float* Cf, bf16* Cb,
                               int M, int N, int Kd, int lda, int ldw, int ldcf, int ldcb,
                               int ldadd, hipStream_t s)
{
    bgemm(ACT, BM, BN, A, W, bias, addv, Cf, Cb, M, N, Kd, lda, ldw, ldcf, ldcb, ldadd,
          1, 1, 0, 0, 0, 0, 0, 0, 0, 0, 0, s);
}

// =====================================================================
// Flash cross-attention, KV-split (verified round 12).
// =====================================================================
__global__ __launch_bounds__(128)
void flash_split_kernel(const bf16* __restrict__ Qp, const bf16* __restrict__ Kp,
                        const bf16* __restrict__ VTp, float* __restrict__ OP,
                        float2* __restrict__ ML, float scale)
{
    const int qt = blockIdx.x;            // 0..31
    const int bh = blockIdx.y;            // b*H + h
    const int sp = blockIdx.z;            // 0..3
    const int b = bh >> 2, h = bh & 3;
    const int tid = threadIdx.x;
    const int w = tid >> 6;               // 0..1
    const int lane = tid & 63;
    const int rc = lane & 15, hi = lane >> 4;
    const int rlo = rc & 7;

    __shared__ bf16 Ks[64 * 128];
    __shared__ bf16 Vs[128 * 64];
    __shared__ bf16 Ps[32 * 64];

    {
        const bf16* qb = Qp + ((long)(b * cL + qt * 32)) * cDM + h * cHD;
#pragma unroll
        for (int c = 0; c < 4; c++) {
            const int row = w * 16 + c * 4 + (lane >> 4);
            const int gc = (lane & 15) ^ (row & 7);
            GLL16(qb + (long)row * cDM + gc * 8, Ks + (w * 16 + c * 4) * 128);
        }
    }
    asm volatile("s_waitcnt vmcnt(0)" ::: "memory");
    __syncthreads();
    short8x aq[4];
#pragma unroll
    for (int kk = 0; kk < 4; kk++) {
        const int sc = (kk * 4 + hi) ^ rlo;
        aq[kk] = *(const short8x*)(Ks + (w * 16 + rc) * 128 + sc * 8);
    }
    __syncthreads();   // Ks free for K tiles

    float m_r[4], l_r[4];
#pragma unroll
    for (int r = 0; r < 4; r++) { m_r[r] = -1e30f; l_r[r] = 0.f; }
    f32x4 oacc[8] = {};

    const bf16* kb0 = Kp + ((long)(b * cLE)) * (2 * cDM) + h * cHD;
    const bf16* vb0 = VTp + ((long)(b * cDM + h * cHD)) * cLE;

    for (int t = 0; t < 4; t++) {
        const int kt = sp * 4 + t;
        __syncthreads();
#pragma unroll
        for (int c = 0; c < 8; c++) {
            const int row = w * 32 + c * 4 + (lane >> 4);
            const int gc = (lane & 15) ^ (row & 7);
            GLL16(kb0 + ((long)(kt * 64 + row)) * (2 * cDM) + gc * 8,
                  Ks + (w * 32 + c * 4) * 128);
        }
#pragma unroll
        for (int c = 0; c < 8; c++) {
            const int row = w * 64 + c * 8 + (lane >> 3);
            const int gc = (lane & 7) ^ (row & 7);
            GLL16(vb0 + (long)row * cLE + kt * 64 + gc * 8,
                  Vs + (w * 64 + c * 8) * 64);
        }
        asm volatile("s_waitcnt vmcnt(0)" ::: "memory");
        __syncthreads();

        f32x4 s[4] = {};
#pragma unroll
        for (int kk = 0; kk < 4; kk++) {
            const int sc = (kk * 4 + hi) ^ rlo;
#pragma unroll
            for (int j = 0; j < 4; j++) {
                short8x bk = *(const short8x*)(Ks + (j * 16 + rc) * 128 + sc * 8);
                s[j] = __builtin_amdgcn_mfma_f32_16x16x32_bf16(aq[kk], bk, s[j], 0, 0, 0);
            }
        }

        float p[4][4];
        float esc[4];
#pragma unroll
        for (int r = 0; r < 4; r++) {
            const float v0 = s[0][r] * scale, v1 = s[1][r] * scale;
            const float v2 = s[2][r] * scale, v3 = s[3][r] * scale;
            float mx = fmaxf(fmaxf(v0, v1), fmaxf(v2, v3));
            mx = fmaxf(mx, __shfl_xor(mx, 1));
            mx = fmaxf(mx, __shfl_xor(mx, 2));
            mx = fmaxf(mx, __shfl_xor(mx, 4));
            mx = fmaxf(mx, __shfl_xor(mx, 8));
            const float mn = fmaxf(m_r[r], mx);
            p[0][r] = __expf(v0 - mn);
            p[1][r] = __expf(v1 - mn);
            p[2][r] = __expf(v2 - mn);
            p[3][r] = __expf(v3 - mn);
            float rs = (p[0][r] + p[1][r]) + (p[2][r] + p[3][r]);
            rs += __shfl_xor(rs, 1);
            rs += __shfl_xor(rs, 2);
            rs += __shfl_xor(rs, 4);
            rs += __shfl_xor(rs, 8);
            esc[r] = __expf(m_r[r] - mn);
            l_r[r] = l_r[r] * esc[r] + rs;
            m_r[r] = mn;
        }
#pragma unroll
        for (int j2 = 0; j2 < 8; j2++)
#pragma unroll
            for (int r = 0; r < 4; r++)
                oacc[j2][r] *= esc[r];
#pragma unroll
        for (int j = 0; j < 4; j++)
#pragma unroll
            for (int r = 0; r < 4; r++) {
                const int q = w * 16 + hi * 4 + r;
                const int cp = (j * 2 + (rc >> 3)) ^ (q & 7);
                Ps[q * 64 + cp * 8 + (rc & 7)] = __float2bfloat16(p[j][r]);
            }
        __syncthreads();
#pragma unroll
        for (int ks = 0; ks < 2; ks++) {
            const int sc = (ks * 4 + hi) ^ rlo;
            short8x ap = *(const short8x*)(Ps + (w * 16 + rc) * 64 + sc * 8);
#pragma unroll
            for (int j2 = 0; j2 < 8; j2++) {
                short8x bv = *(const short8x*)(Vs + (j2 * 16 + rc) * 64 + sc * 8);
                oacc[j2] = __builtin_amdgcn_mfma_f32_16x16x32_bf16(ap, bv, oacc[j2], 0, 0, 0);
            }
        }
    }

    float* ob = OP + (((long)sp * (cB * cL) + b * cL + qt * 32)) * cDM + h * cHD;
#pragma unroll
    for (int j2 = 0; j2 < 8; j2++)
#pragma unroll
        for (int r = 0; r < 4; r++)
            ob[(long)(w * 16 + hi * 4 + r) * cDM + j2 * 16 + rc] = oacc[j2][r];
    if (rc == 0) {
#pragma unroll
        for (int r = 0; r < 4; r++) {
            const int row = qt * 32 + w * 16 + hi * 4 + r;
            ML[(((long)sp * cB + b) * cH + h) * cL + row] = make_float2(m_r[r], l_r[r]);
        }
    }
}

// =====================================================================
// Combine flash splits (verified round 12).
// =====================================================================
__global__ __launch_bounds__(256)
void flash_combine_kernel(const float* __restrict__ OP, const float2* __restrict__ ML,
                          bf16* __restrict__ Op)
{
    const int row = blockIdx.x;        // 0..2047
    const int b = row >> 10, lr = row & 1023;
    const int t = threadIdx.x;
    __shared__ float ms[cSPL][cH], ls[cSPL][cH];
    __shared__ float wgt[cSPL][cH], linv[cH];
    if (t < cSPL * cH) {
        const int s = t >> 2, h = t & 3;
        float2 v = ML[(((long)s * cB + b) * cH + h) * cL + lr];
        ms[s][h] = v.x; ls[s][h] = v.y;
    }
    __syncthreads();
    if (t < cH) {
        const int h = t;
        float M = fmaxf(fmaxf(ms[0][h], ms[1][h]), fmaxf(ms[2][h], ms[3][h]));
        float L = 0.f;
#pragma unroll
        for (int s = 0; s < cSPL; s++) {
            const float e = __expf(ms[s][h] - M);
            wgt[s][h] = e;
            L += e * ls[s][h];
        }
        linv[h] = 1.f / L;
    }
    __syncthreads();
#pragma unroll
    for (int c0 = 0; c0 < 2; c0++) {
        const int col = t + c0 * 256;
        const int h = col >> 7;
        float o = 0.f;
#pragma unroll
        for (int s = 0; s < cSPL; s++)
            o += wgt[s][h] * OP[((long)s * (cB * cL) + row) * cDM + col];
        Op[(long)row * cDM + col] = __float2bfloat16(o * linv[h]);
    }
}

// =====================================================================
// split-K partial reduce:  out = sum_s parts[s]  (f32 + bf16 outputs)
// =====================================================================
__global__ void splitk_reduce_kernel(const float* __restrict__ parts, float* __restrict__ outf,
                                     bf16* __restrict__ outb, int n4, int sliceN4, int S)
{
    const int i = blockIdx.x * 256 + threadIdx.x;
    if (i >= n4) return;
    float4 a = ((const float4*)parts)[i];
    for (int s2 = 1; s2 < S; s2++) {
        float4 b2 = ((const float4*)parts)[i + (long)s2 * sliceN4];
        a.x += b2.x; a.y += b2.y; a.z += b2.z; a.w += b2.w;
    }
    ((float4*)outf)[i] = a;
    bf16 b0 = __float2bfloat16(a.x), b1 = __float2bfloat16(a.y);
    bf16 b2 = __float2bfloat16(a.z), b3 = __float2bfloat16(a.w);
    short4 pk = { *(short*)&b0, *(short*)&b1, *(short*)&b2, *(short*)&b3 };
    ((short4*)outb)[i] = pk;
}

// =====================================================================
// One-shot fused f32->bf16 conversion of all weight tensors + enc.
// =====================================================================
__global__ void cvt_all_kernel(
    const float* __restrict__ s0, bf16* __restrict__ d0,   // enc
    const float* __restrict__ s1, bf16* __restrict__ d1,   // m_in_w
    const float* __restrict__ s2, bf16* __restrict__ d2,   // m_xproj
    const float* __restrict__ s3, bf16* __restrict__ d3,   // m_dt_w
    const float* __restrict__ s4, bf16* __restrict__ d4,   // m_out_w
    const float* __restrict__ s5, bf16* __restrict__ d5,   // a_in_w
    const float* __restrict__ s6, bf16* __restrict__ d6,   // a_out_w
    const float* __restrict__ s7, bf16* __restrict__ d7)   // W_out
{
    constexpr long E0 = 1048576, E1 = 4194304, E2 = 262144, E3 = 131072;
    constexpr long E4 = 2097152, E5 = 3145728, E6 = 1048576, E7 = 40960;
    constexpr long C0 = E0, C1 = C0 + E1, C2 = C1 + E2, C3 = C2 + E3;
    constexpr long C4 = C3 + E4, C5 = C4 + E5, C6 = C5 + E6, C7 = C6 + E7;
    long i = ((long)blockIdx.x * 256 + threadIdx.x) * 4;
    if (i >= C7) return;
    const float* s; bf16* d;
    if      (i < C0) { s = s0; d = d0; }
    else if (i < C1) { s = s1; d = d1; i -= C0; }
    else if (i < C2) { s = s2; d = d2; i -= C1; }
    else if (i < C3) { s = s3; d = d3; i -= C2; }
    else if (i < C4) { s = s4; d = d4; i -= C3; }
    else if (i < C5) { s = s5; d = d5; i -= C4; }
    else if (i < C6) { s = s6; d = d6; i -= C5; }
    else             { s = s7; d = d7; i -= C6; }
    float4 v = *(const float4*)(s + i);
    d[i]     = __float2bfloat16(v.x);
    d[i + 1] = __float2bfloat16(v.y);
    d[i + 2] = __float2bfloat16(v.z);
    d[i + 3] = __float2bfloat16(v.w);
}

// f32 (rows x kin) -> bf16 (rows x kout), zero-padded beyond kin
__global__ void cvt_pad_kernel(const float* __restrict__ in, bf16* __restrict__ out,
                               int rows, int kin, int kout)
{
    const int idx = blockIdx.x * 256 + threadIdx.x;
    if (idx >= rows * kout) return;
    const int r = idx / kout, k = idx - r * kout;
    out[idx] = __float2bfloat16(k < kin ? in[(long)r * kin + k] : 0.f);
}

// =====================================================================
// bf16 transpose, batched over (layer, batch):  z = lay*cB + b.
// =====================================================================
__global__ void transpose_bf16_kernel(const bf16* __restrict__ in, bf16* __restrict__ out,
                                      int ldin, int col0, long inLS, long outLS)
{
    __shared__ bf16 t[32][33];
    const int z = blockIdx.z;
    const int lay = z >> 1, b = z & 1;
    in  += (long)lay * inLS;
    out += (long)lay * outLS;
    const int le0 = blockIdx.x * 32, d0 = blockIdx.y * 32;
    const int tid = threadIdx.x;
    const int c = tid & 31, r = tid >> 5;
    for (int i = r; i < 32; i += 8)
        t[i][c] = in[((long)b * cLE + le0 + i) * ldin + col0 + d0 + c];
    __syncthreads();
    for (int i = r; i < 32; i += 8)
        out[((long)b * cDM + d0 + i) * cLE + le0 + c] = t[c][i];
}

// =====================================================================
// RMSNorm per row — layer-0 entry
// =====================================================================
__global__ void rmsnorm_kernel(const float* __restrict__ x, const float* __restrict__ w,
                               float* __restrict__ outf, bf16* __restrict__ outb, int Dm)
{
    const int row = blockIdx.x;
    const float* xr = x + (long)row * Dm;
    float s = 0.f;
    for (int i = threadIdx.x; i < Dm; i += 256) { float v = xr[i]; s += v * v; }
    __shared__ float red[5];
    const int lane = threadIdx.x & 63, wv = threadIdx.x >> 6;
#pragma unroll
    for (int off = 1; off < 64; off <<= 1) s += __shfl_xor(s, off);
    if (lane == 0) red[wv] = s;
    __syncthreads();
    if (threadIdx.x == 0) {
        float t = red[0] + red[1] + red[2] + red[3];
        red[4] = rsqrtf(t / Dm + 1e-5f);
    }
    __syncthreads();
    const float scale = red[4];
    for (int i = threadIdx.x; i < Dm; i += 256) {
        float v = xr[i] * scale * w[i];
        if (outf) outf[(long)row * Dm + i] = v;
        if (outb) outb[(long)row * Dm + i] = __float2bfloat16(v);
    }
}

// =====================================================================
// LayerNorm per row (Dm=512, 2 elems/thread) + fused next-RMS.
// =====================================================================
__global__ void layernorm_kernel(const float* __restrict__ x, const float* __restrict__ w,
                                 const float* __restrict__ b, float* __restrict__ outf,
                                 bf16* __restrict__ outb,
                                 const float* __restrict__ rms_w, bf16* __restrict__ rms_out)
{
    const int row = blockIdx.x;
    const float* xr = x + (long)row * 512;
    const int t = threadIdx.x;
    const int i0 = t, i1 = t + 256;
    float x0 = xr[i0], x1 = xr[i1];
    float s = x0 + x1, sq = x0 * x0 + x1 * x1;
    __shared__ float red[8];
    __shared__ float mv[2];
    const int lane = t & 63, wv = t >> 6;
#pragma unroll
    for (int off = 1; off < 64; off <<= 1) { s += __shfl_xor(s, off); sq += __shfl_xor(sq, off); }
    if (lane == 0) { red[wv] = s; red[4 + wv] = sq; }
    __syncthreads();
    if (t == 0) {
        float ts = red[0] + red[1] + red[2] + red[3];
        float tq = red[4] + red[5] + red[6] + red[7];
        float m = ts / 512.f;
        float var = tq / 512.f - m * m;
        mv[0] = m;
        mv[1] = rsqrtf(var + 1e-5f);
    }
    __syncthreads();
    const float m = mv[0], rs = mv[1];
    const float v0 = (x0 - m) * rs * w[i0] + b[i0];
    const float v1 = (x1 - m) * rs * w[i1] + b[i1];
    outf[(long)row * 512 + i0] = v0;
    outf[(long)row * 512 + i1] = v1;
    outb[(long)row * 512 + i0] = __float2bfloat16(v0);
    outb[(long)row * 512 + i1] = __float2bfloat16(v1);
    float s2 = v0 * v0 + v1 * v1;
#pragma unroll
    for (int off = 1; off < 64; off <<= 1) s2 += __shfl_xor(s2, off);
    if (lane == 0) red[wv] = s2;
    __syncthreads();
    if (t == 0) mv[0] = rsqrtf((red[0] + red[1] + red[2] + red[3]) / 512.f + 1e-5f);
    __syncthreads();
    const float rsc = mv[0];
    rms_out[(long)row * 512 + i0] = __float2bfloat16(v0 * rsc * rms_w[i0]);
    rms_out[(long)row * 512 + i1] = __float2bfloat16(v1 * rsc * rms_w[i1]);
}

// =====================================================================
// Causal depthwise conv (K=4) + bias + SiLU -> xm f32 + bf16
// =====================================================================
__global__ void conv_silu_kernel(const float* __restrict__ xr, const float* __restrict__ w,
                                 const float* __restrict__ bias, float* __restrict__ xm,
                                 bf16* __restrict__ xmb)
{
    const int idx = blockIdx.x * 256 + threadIdx.x;
    if (idx >= cB * cL * cDI) return;
    const int d = idx & (cDI - 1);
    const int l = (idx >> 10) & (cL - 1);
    const int b = idx >> 20;
    float s = bias[d];
#pragma unroll
    for (int j = 0; j < cKC; j++) {
        const int ls = l + j - (cKC - 1);
        if (ls >= 0) s += w[d * cKC + j] * xr[((long)(b * cL + ls)) * (2 * cDI) + d];
    }
    s = s / (1.f + __expf(-s));
    xm[(long)idx] = s;
    xmb[(long)idx] = __float2bfloat16(s);
}

// =====================================================================
// FUSED selective scan: one block per (b,d); 256 threads = 64 chunks x 4 ng.
//   pass 1: per-chunk local scan (16 steps) -> (aprod, send) per n
//   LDS Hillis-Steele scan over chunks (affine composition, 6 steps)
//   pass 2: re-run chunk from incoming state, reduce over n, gated y write
// =====================================================================
__global__ __launch_bounds__(256)
void scan_fused_kernel(const float* __restrict__ xm, const float* __restrict__ delta,
                       const float* __restrict__ xdbl, const float* __restrict__ Alog,
                       const float* __restrict__ Dv, const float* __restrict__ xr,
                       bf16* __restrict__ y)
{
    const int blk = blockIdx.x;          // b*cDI + d
    const int d = blk & (cDI - 1);
    const int b = blk >> 10;
    const int tid = threadIdx.x;
    const int ch = tid >> 2;             // 0..63
    const int ng = tid & 3;              // 0..3

    const float4 Al = *(const float4*)(Alog + d * cDS + 4 * ng);
    const float A0 = -__expf(Al.x), A1 = -__expf(Al.y), A2 = -__expf(Al.z), A3 = -__expf(Al.w);
    const float Dval = Dv[d];

    const int l0 = ch * cCHL;
    const float* dp = delta + (long)(b * cL + l0) * cDI + d;
    const float* up = xm    + (long)(b * cL + l0) * cDI + d;
    const float* xb = xdbl  + (long)(b * cL + l0) * 64 + cDTR + 4 * ng;
    const float* xc = xb + cDS;
    const float* rp = xr + (long)(b * cL + l0) * (2 * cDI) + cDI + d;
    bf16* yp = y + (long)(b * cL + l0) * cDI + d;

    // ---- pass 1: local chunk scan ----
    float s0 = 0.f, s1 = 0.f, s2 = 0.f, s3 = 0.f;
    float p0 = 1.f, p1 = 1.f, p2 = 1.f, p3 = 1.f;
#pragma unroll
    for (int t = 0; t < cCHL; t++) {
        const float dl = dp[(long)t * cDI];
        const float du = dl * up[(long)t * cDI];
        const float4 Bv = *(const float4*)(xb + (long)t * 64);
        const float a0 = __expf(dl * A0), a1 = __expf(dl * A1);
        const float a2 = __expf(dl * A2), a3 = __expf(dl * A3);
        s0 = a0 * s0 + du * Bv.x; p0 *= a0;
        s1 = a1 * s1 + du * Bv.y; p1 *= a1;
        s2 = a2 * s2 + du * Bv.z; p2 *= a2;
        s3 = a3 * s3 + du * Bv.w; p3 *= a3;
    }

    // ---- LDS affine scan over chunks ----
    __shared__ float As[cNCH][17], Ss[cNCH][17];
    As[ch][4 * ng + 0] = p0; Ss[ch][4 * ng + 0] = s0;
    As[ch][4 * ng + 1] = p1; Ss[ch][4 * ng + 1] = s1;
    As[ch][4 * ng + 2] = p2; Ss[ch][4 * ng + 2] = s2;
    As[ch][4 * ng + 3] = p3; Ss[ch][4 * ng + 3] = s3;
    __syncthreads();
    for (int st = 1; st < cNCH; st <<= 1) {
        float na[4], nb[4];
        const bool act = (ch >= st);
        if (act) {
#pragma unroll
            for (int j = 0; j < 4; j++) {
                const int n = 4 * ng + j;
                const float ah = As[ch][n], bh = Ss[ch][n];
                na[j] = ah * As[ch - st][n];
                nb[j] = ah * Ss[ch - st][n] + bh;
            }
        }
        __syncthreads();
        if (act) {
#pragma unroll
            for (int j = 0; j < 4; j++) {
                const int n = 4 * ng + j;
                As[ch][n] = na[j];
                Ss[ch][n] = nb[j];
            }
        }
        __syncthreads();
    }
    // incoming state for this chunk = Ss[ch-1] (0 for ch==0)
    if (ch > 0) {
        s0 = Ss[ch - 1][4 * ng + 0];
        s1 = Ss[ch - 1][4 * ng + 1];
        s2 = Ss[ch - 1][4 * ng + 2];
        s3 = Ss[ch - 1][4 * ng + 3];
    } else {
        s0 = s1 = s2 = s3 = 0.f;
    }

    // ---- pass 2: re-run with incoming state, produce y ----
#pragma unroll
    for (int t = 0; t < cCHL; t++) {
        const float dl = dp[(long)t * cDI];
        const float u  = up[(long)t * cDI];
        const float du = dl * u;
        const float4 Bv = *(const float4*)(xb + (long)t * 64);
        const float4 Cv = *(const float4*)(xc + (long)t * 64);
        const float a0 = __expf(dl * A0), a1 = __expf(dl * A1);
        const float a2 = __expf(dl * A2), a3 = __expf(dl * A3);
        s0 = a0 * s0 + du * Bv.x;
        s1 = a1 * s1 + du * Bv.y;
        s2 = a2 * s2 + du * Bv.z;
        s3 = a3 * s3 + du * Bv.w;
        float c = s0 * Cv.x;
        c = fmaf(s1, Cv.y, c);
        c = fmaf(s2, Cv.z, c);
        c = fmaf(s3, Cv.w, c);
        c += __shfl_xor(c, 1);
        c += __shfl_xor(c, 2);
        if (ng == 0) {
            const float res = rp[(long)t * 2 * cDI];
            const float sig = 1.f / (1.f + __expf(-res));
            yp[(long)t * cDI] = __float2bfloat16((c + u * Dval) * (res * sig));
        }
    }
}

// =====================================================================
extern "C" void kernel_launch(void* const* d_in, const int* in_sizes, int n_in,
                              void* d_out, int out_size, void* d_ws, size_t ws_size,
                              hipStream_t stream)
{
    const float* x       = (const float*)d_in[0];
    const float* enc     = (const float*)d_in[1];
    const float* W_in    = (const float*)d_in[2];
    const float* b_in    = (const float*)d_in[3];
    const float* m_norm_w= (const float*)d_in[4];
    const float* m_in_w  = (const float*)d_in[5];
    const float* m_conv_w= (const float*)d_in[6];
    const float* m_conv_b= (const float*)d_in[7];
    const float* m_xproj = (const float*)d_in[8];
    const float* m_dt_w  = (const float*)d_in[9];
    const float* m_dt_b  = (const float*)d_in[10];
    const float* m_Alog  = (const float*)d_in[11];
    const float* m_D     = (const float*)d_in[12];
    const float* m_out_w = (const float*)d_in[13];
    const float* a_in_w  = (const float*)d_in[14];
    const float* a_in_b  = (const float*)d_in[15];
    const float* a_out_w = (const float*)d_in[16];
    const float* a_out_b = (const float*)d_in[17];
    const float* a_ln_w  = (const float*)d_in[18];
    const float* a_ln_b  = (const float*)d_in[19];
    const float* normf_w = (const float*)d_in[20];
    const float* W_out   = (const float*)d_in[21];
    float* out = (float*)d_out;

    float* ws = (float*)d_ws;
    long off = 0;
    auto allocf = [&](long n) { float* p = ws + off; off += n; return p; };

    const long M1 = 1 << 20;
    float* bufH    = allocf(M1);
    float* bufPre  = allocf(M1);         // also xproj split-K partials
    float* bufXR   = allocf(4 * M1);
    float* bufXM   = allocf(2 * M1);
    float* bufDelta= allocf(2 * M1);
    float* bufXDBL = allocf(M1 / 8);
    bf16* bufU    = (bf16*)allocf(M1 / 2);      // 2048x512 bf16 (rms output)
    bf16* bufHb   = (bf16*)allocf(M1 / 2);
    bf16* bufXMb  = (bf16*)allocf(M1);          // 2048x1024 bf16
    bf16* bufXDBLb= (bf16*)allocf(M1 / 16);
    bf16* bufY    = (bf16*)allocf(M1);          // 2048x1024 bf16
    bf16* bufQ    = (bf16*)allocf(M1 / 2);
    bf16* bufO    = (bf16*)allocf(M1 / 2);
    bf16* encb    = (bf16*)allocf(M1 / 2);
    bf16* w_in_b  = (bf16*)allocf(2 * M1);
    bf16* w_xp_b  = (bf16*)allocf(M1 / 8);
    bf16* w_dt_b  = (bf16*)allocf(M1 / 16);
    bf16* w_out_b = (bf16*)allocf(M1);
    bf16* w_ain_b = (bf16*)allocf(3 * M1 / 2);
    bf16* w_aout_b= (bf16*)allocf(M1 / 2);
    bf16* x_pad   = (bf16*)allocf(2048L * 96 / 2);
    bf16* w_inp_b = (bf16*)allocf(512L * 96 / 2);
    bf16* w_outf_b= (bf16*)allocf(80L * 512 / 2);
    bf16* bufKV4  = (bf16*)allocf(4 * M1);      // 4 layers x 2M bf16
    bf16* bufVT4  = (bf16*)allocf(2 * M1);      // 4 layers x 1M bf16
    float* bufOP  = allocf(4 * M1);             // flash partials [4][2048][512] f32
    float2* bufML = (float2*)allocf(M1 / 16);   // [4][2][4][1024] float2

    const int Mrows = cB * cL;   // 2048
    const long kvLS = (long)Mrows * 2 * cDM;
    const long vtLS = (long)cB * cDM * cLE;

    // ---- one-time conversions ----
    cvt_all_kernel<<<11688, 256, 0, stream>>>(
        enc, encb, m_in_w, w_in_b, m_xproj, w_xp_b, m_dt_w, w_dt_b,
        m_out_w, w_out_b, a_in_w, w_ain_b, a_out_w, w_aout_b, W_out, w_outf_b);
    cvt_pad_kernel<<<(Mrows * 96 + 255) / 256, 256, 0, stream>>>(x, x_pad, Mrows, cNM, 96);
    cvt_pad_kernel<<<(cDM * 96 + 255) / 256, 256, 0, stream>>>(W_in, w_inp_b, cDM, cNM, 96);

    // ---- all-layer K|V projection + V^T ----
    bgemm(0, 64, 128, encb, w_ain_b + (long)cDM * cDM, a_in_b + cDM, nullptr, nullptr, bufKV4,
          Mrows, 2 * cDM, cDM, cDM, cDM, 0, 2 * cDM, 0,
          cLAYERS, 1,
          0, 0,
          (long)3 * cDM * cDM, 0,
          0, 0, kvLS, 0,
          (long)3 * cDM,
          stream);
    {
        dim3 g(cLE / 32, cDM / 32, cLAYERS * cB);
        transpose_bf16_kernel<<<g, 256, 0, stream>>>(bufKV4, bufVT4, 2 * cDM, cDM, kvLS, vtLS);
    }

    // h = x @ W_in.T + b_in ; layer-0 rmsnorm -> bufU
    bgemm_plain(0, 64, 64, x_pad, w_inp_b, b_in, nullptr, bufH, nullptr,
                Mrows, cDM, 96, 96, 96, cDM, 0, 0, stream);
    rmsnorm_kernel<<<Mrows, 256, 0, stream>>>(bufH, m_norm_w, nullptr, bufU, cDM);

    for (int i = 0; i < cLAYERS; i++) {
        const bf16*  in_w   = w_in_b   + (long)i * 2 * cDI * cDM;
        const float* conv_w = m_conv_w + (long)i * cDI * cKC;
        const float* conv_b = m_conv_b + (long)i * cDI;
        const bf16*  xproj  = w_xp_b   + (long)i * 64 * cDI;
        const bf16*  dt_w   = w_dt_b   + (long)i * cDI * cDTR;
        const float* dt_b   = m_dt_b   + (long)i * cDI;
        const float* Alog   = m_Alog   + (long)i * cDI * cDS;
        const float* Dv     = m_D      + (long)i * cDI;
        const bf16*  out_w  = w_out_b  + (long)i * cDM * cDI;
        const bf16*  ain_w  = w_ain_b  + (long)i * 3 * cDM * cDM;
        const float* ain_b  = a_in_b   + (long)i * 3 * cDM;
        const bf16*  aout_w = w_aout_b + (long)i * cDM * cDM;
        const float* aout_b = a_out_b  + (long)i * cDM;
        const float* ln_w   = a_ln_w   + (long)i * cDM;
        const float* ln_b   = a_ln_b   + (long)i * cDM;
        const bf16*  kv_l   = bufKV4 + (long)i * kvLS;
        const bf16*  vt_l   = bufVT4 + (long)i * vtLS;
        const float* next_rms_w = (i + 1 < cLAYERS) ? (m_norm_w + (long)(i + 1) * cDM) : normf_w;

        // ---- mamba (bufU holds rmsnorm(h) bf16) ----
        bgemm_plain(0, 64, 128, bufU, in_w, nullptr, nullptr, bufXR, nullptr,
                    Mrows, 2 * cDI, cDM, cDM, cDM, 2 * cDI, 0, 0, stream);
        conv_silu_kernel<<<(cB * cL * cDI) / 256, 256, 0, stream>>>(bufXR, conv_w, conv_b, bufXM, bufXMb);
        bgemm(0, 64, 64, bufXMb, xproj, nullptr, nullptr, bufPre, nullptr,
              Mrows, 64, cDI / 8, cDI, cDI, 64, 0, 0,
              8, 1, 128, 0, 128, 0, (long)Mrows * 64, 0, 0, 0, 0, stream);
        splitk_reduce_kernel<<<(Mrows * 64 / 4 + 255) / 256, 256, 0, stream>>>(
            bufPre, bufXDBL, bufXDBLb, Mrows * 64 / 4, Mrows * 64 / 4, 8);
        bgemm_plain(1, 64, 128, bufXDBLb, dt_w, dt_b, nullptr, bufDelta, nullptr,
                    Mrows, cDI, cDTR, 64, cDTR, cDI, 0, 0, stream);
        // fused single-kernel scan (2048 blocks, full occupancy)
        scan_fused_kernel<<<cB * cDI, 256, 0, stream>>>(bufXM, bufDelta, bufXDBL, Alog, Dv,
                                                        bufXR, bufY);
        bgemm_plain(0, 64, 64, bufY, out_w, nullptr, bufH, bufH, bufHb,
                    Mrows, cDM, cDI, cDI, cDI, cDM, cDM, cDM, stream);

        // ---- cross attention: Q gemm -> split flash -> combine ----
        bgemm_plain(0, 64, 64, bufHb, ain_w, ain_b, nullptr, nullptr, bufQ,
                    Mrows, cDM, cDM, cDM, cDM, 0, cDM, 0, stream);
        {
            dim3 g(cL / 32, cB * cH, cSPL);
            flash_split_kernel<<<g, 128, 0, stream>>>(bufQ, kv_l, vt_l, bufOP, bufML,
                                                      0.08838834764831845f);
        }
        flash_combine_kernel<<<Mrows, 256, 0, stream>>>(bufOP, bufML, bufO);
        // pre = o @ aout_w.T + aout_b + h ; h = LN(pre) (+ fused next-RMS -> bufU)
        bgemm_plain(0, 64, 64, bufO, aout_w, aout_b, bufH, bufPre, nullptr,
                    Mrows, cDM, cDM, cDM, cDM, cDM, 0, cDM, stream);
        layernorm_kernel<<<Mrows, 256, 0, stream>>>(bufPre, ln_w, ln_b, bufH, bufHb,
                                                    next_rms_w, bufU);
    }

    // final: out = bufU(= rms(h, normf_w)) @ W_out.T
    bgemm_plain(0, 64, 64, bufU, w_outf_b, nullptr, nullptr, out, nullptr,
                Mrows, cNM, cDM, cDM, cDM, cNM, 0, 0, stream);
}

// Round 14
// 742.651 us; speedup vs baseline: 1.2283x; 1.2283x over previous
//
#include <hip/hip_runtime.h>
#include <hip/hip_bf16.h>
#include <math.h>

typedef __hip_bfloat16 bf16;
typedef __attribute__((ext_vector_type(8))) short short8x;
typedef __attribute__((ext_vector_type(4))) float f32x4;

// ---- problem constants ----
static constexpr int cB   = 2;
static constexpr int cL   = 1024;
static constexpr int cLE  = 1024;
static constexpr int cNM  = 80;
static constexpr int cDM  = 512;
static constexpr int cLAYERS = 4;
static constexpr int cDS  = 16;
static constexpr int cKC  = 4;     // conv taps
static constexpr int cH   = 4;     // heads
static constexpr int cDI  = 1024;  // EXP*DM
static constexpr int cDTR = 32;
static constexpr int cHD  = 128;   // head dim

static constexpr int cNCH = 64;    // scan chunks (bit extraction assumes 64)
static constexpr int cCHL = cL / cNCH;  // 16 steps per chunk
static constexpr int cSPL = 4;     // flash KV splits

#define GLL16(g, l) __builtin_amdgcn_global_load_lds( \
    (const __attribute__((address_space(1))) void*)(g), \
    (__attribute__((address_space(3))) void*)(l), 16, 0, 0)

// =====================================================================
// bf16 MFMA GEMM, BMxBN tile, 4 waves (2x2), K-step 32.
// =====================================================================
template<int ACT, int BM, int BN>
__global__ __launch_bounds__(256)
void bgemm_kernel(const bf16* __restrict__ A, const bf16* __restrict__ W,
                  const float* __restrict__ bias, const float* __restrict__ addv,
                  float* __restrict__ Cf, bf16* __restrict__ Cb,
                  int M, int N, int Kd, int lda, int ldw, int ldcf, int ldcb, int ldadd,
                  int bdiv, long sA1, long sA2, long sW1, long sW2,
                  long sCf1, long sCf2, long sCb1, long sCb2, long sBias)
{
    constexpr int RM = BM / 32;
    constexpr int RN = BN / 32;
    const int z = blockIdx.z;
    const int i1 = z / bdiv, i2 = z % bdiv;
    A += i1 * sA1 + i2 * sA2;
    W += i1 * sW1 + i2 * sW2;
    if (bias) bias += i1 * sBias;

    const int bm = blockIdx.y * BM;
    const int bn = blockIdx.x * BN;
    const int tid = threadIdx.x;
    const int lane = tid & 63;
    const int wid = tid >> 6;
    const int wr = wid >> 1, wc = wid & 1;

    __shared__ bf16 As[BM * 32];
    __shared__ bf16 Bs[BN * 32];

    f32x4 acc[RM][RN] = {};

    const int r_in = lane >> 2;
    const int kb   = (lane & 3) * 8;
    const int hi   = lane >> 4;
    const int rc   = lane & 15;

    for (int k0 = 0; k0 < Kd; k0 += 32) {
#pragma unroll
        for (int iss = 0; iss < BM / 64; iss++) {
            const int row = wid * (BM / 4) + iss * 16 + r_in;
            int gm = bm + row; if (gm >= M) gm = M - 1;
            const bf16* ga = A + (long)gm * lda + k0 + kb;
            GLL16(ga, As + (wid * (BM / 4) + iss * 16) * 32);
        }
#pragma unroll
        for (int iss = 0; iss < BN / 64; iss++) {
            const int row = wid * (BN / 4) + iss * 16 + r_in;
            int gn = bn + row; if (gn >= N) gn = N - 1;
            const bf16* gb = W + (long)gn * ldw + k0 + kb;
            GLL16(gb, Bs + (wid * (BN / 4) + iss * 16) * 32);
        }
        asm volatile("s_waitcnt vmcnt(0)" ::: "memory");
        __syncthreads();

        short8x af[RM], bfv[RN];
#pragma unroll
        for (int i = 0; i < RM; i++)
            af[i] = *(const short8x*)(As + (wr * (BM / 2) + i * 16 + rc) * 32 + hi * 8);
#pragma unroll
        for (int j = 0; j < RN; j++)
            bfv[j] = *(const short8x*)(Bs + (wc * (BN / 2) + j * 16 + rc) * 32 + hi * 8);
#pragma unroll
        for (int i = 0; i < RM; i++)
#pragma unroll
            for (int j = 0; j < RN; j++)
                acc[i][j] = __builtin_amdgcn_mfma_f32_16x16x32_bf16(af[i], bfv[j], acc[i][j], 0, 0, 0);
        __syncthreads();
    }

    const long cfo = i1 * sCf1 + i2 * sCf2;
    const long cbo = i1 * sCb1 + i2 * sCb2;
#pragma unroll
    for (int i = 0; i < RM; i++) {
#pragma unroll
        for (int r = 0; r < 4; r++) {
            const int gm = bm + wr * (BM / 2) + i * 16 + hi * 4 + r;
            if (gm >= M) continue;
#pragma unroll
            for (int j = 0; j < RN; j++) {
                const int gn = bn + wc * (BN / 2) + j * 16 + rc;
                if (gn >= N) continue;
                float v = acc[i][j][r];
                if (bias) v += bias[gn];
                if (ACT == 1) v = (v > 20.f) ? v : log1pf(__expf(v));
                if (addv) v += addv[cfo + (long)gm * ldadd + gn];
                if (Cf) Cf[cfo + (long)gm * ldcf + gn] = v;
                if (Cb) Cb[cbo + (long)gm * ldcb + gn] = __float2bfloat16(v);
            }
        }
    }
}

static inline void bgemm(int ACT, int BM, int BN, const bf16* A, const bf16* W, const float* bias,
                         const float* addv, float* Cf, bf16* Cb,
                         int M, int N, int Kd, int lda, int ldw, int ldcf, int ldcb, int ldadd,
                         int nz, int bdiv, long sA1, long sA2, long sW1, long sW2,
                         long sCf1, long sCf2, long sCb1, long sCb2, long sBias, hipStream_t s)
{
    dim3 g((N + BN - 1) / BN, (M + BM - 1) / BM, nz), b(256);
#define BG_ARGS A, W, bias, addv, Cf, Cb, M, N, Kd, lda, ldw, ldcf, ldcb, ldadd, \
                bdiv, sA1, sA2, sW1, sW2, sCf1, sCf2, sCb1, sCb2, sBias
    if (BM == 128) {
        if (ACT == 1) bgemm_kernel<1, 128, 128><<<g, b, 0, s>>>(BG_ARGS);
        else          bgemm_kernel<0, 128, 128><<<g, b, 0, s>>>(BG_ARGS);
    } else if (BN == 128) {
        if (ACT == 1) bgemm_kernel<1, 64, 128><<<g, b, 0, s>>>(BG_ARGS);
        else          bgemm_kernel<0, 64, 128><<<g, b, 0, s>>>(BG_ARGS);
    } else {
        bgemm_kernel<0, 64, 64><<<g, b, 0, s>>>(BG_ARGS);
    }
#undef BG_ARGS
}

static inline void bgemm_plain(int ACT, int BM, int BN, const bf16* A, const bf16* W,
                               const float* bias, const float* addv, float* Cf, bf16* Cb,
                               int M, int N, int Kd, int lda, int ldw, int ldcf, int ldcb,
                               int ldadd, hipStream_t s)
{
    bgemm(ACT, BM, BN, A, W, bias, addv, Cf, Cb, M, N, Kd, lda, ldw, ldcf, ldcb, ldadd,
          1, 1, 0, 0, 0, 0, 0, 0, 0, 0, 0, s);
}

// =====================================================================
// Flash cross-attention, KV-split (verified round 12).
// =====================================================================
__global__ __launch_bounds__(128)
void flash_split_kernel(const bf16* __restrict__ Qp, const bf16* __restrict__ Kp,
                        const bf16* __restrict__ VTp, float* __restrict__ OP,
                        float2* __restrict__ ML, float scale)
{
    const int qt = blockIdx.x;            // 0..31
    const int bh = blockIdx.y;            // b*H + h
    const int sp = blockIdx.z;            // 0..3
    const int b = bh >> 2, h = bh & 3;
    const int tid = threadIdx.x;
    const int w = tid >> 6;               // 0..1
    const int lane = tid & 63;
    const int rc = lane & 15, hi = lane >> 4;
    const int rlo = rc & 7;

    __shared__ bf16 Ks[64 * 128];
    __shared__ bf16 Vs[128 * 64];
    __shared__ bf16 Ps[32 * 64];

    {
        const bf16* qb = Qp + ((long)(b * cL + qt * 32)) * cDM + h * cHD;
#pragma unroll
        for (int c = 0; c < 4; c++) {
            const int row = w * 16 + c * 4 + (lane >> 4);
            const int gc = (lane & 15) ^ (row & 7);
            GLL16(qb + (long)row * cDM + gc * 8, Ks + (w * 16 + c * 4) * 128);
        }
    }
    asm volatile("s_waitcnt vmcnt(0)" ::: "memory");
    __syncthreads();
    short8x aq[4];
#pragma unroll
    for (int kk = 0; kk < 4; kk++) {
        const int sc = (kk * 4 + hi) ^ rlo;
        aq[kk] = *(const short8x*)(Ks + (w * 16 + rc) * 128 + sc * 8);
    }
    __syncthreads();   // Ks free for K tiles

    float m_r[4], l_r[4];
#pragma unroll
    for (int r = 0; r < 4; r++) { m_r[r] = -1e30f; l_r[r] = 0.f; }
    f32x4 oacc[8] = {};

    const bf16* kb0 = Kp + ((long)(b * cLE)) * (2 * cDM) + h * cHD;
    const bf16* vb0 = VTp + ((long)(b * cDM + h * cHD)) * cLE;

    for (int t = 0; t < 4; t++) {
        const int kt = sp * 4 + t;
        __syncthreads();
#pragma unroll
        for (int c = 0; c < 8; c++) {
            const int row = w * 32 + c * 4 + (lane >> 4);
            const int gc = (lane & 15) ^ (row & 7);
            GLL16(kb0 + ((long)(kt * 64 + row)) * (2 * cDM) + gc * 8,
                  Ks + (w * 32 + c * 4) * 128);
        }
#pragma unroll
        for (int c = 0; c < 8; c++) {
            const int row = w * 64 + c * 8 + (lane >> 3);
            const int gc = (lane & 7) ^ (row & 7);
            GLL16(vb0 + (long)row * cLE + kt * 64 + gc * 8,
                  Vs + (w * 64 + c * 8) * 64);
        }
        asm volatile("s_waitcnt vmcnt(0)" ::: "memory");
        __syncthreads();

        f32x4 s[4] = {};
#pragma unroll
        for (int kk = 0; kk < 4; kk++) {
            const int sc = (kk * 4 + hi) ^ rlo;
#pragma unroll
            for (int j = 0; j < 4; j++) {
                short8x bk = *(const short8x*)(Ks + (j * 16 + rc) * 128 + sc * 8);
                s[j] = __builtin_amdgcn_mfma_f32_16x16x32_bf16(aq[kk], bk, s[j], 0, 0, 0);
            }
        }

        float p[4][4];
        float esc[4];
#pragma unroll
        for (int r = 0; r < 4; r++) {
            const float v0 = s[0][r] * scale, v1 = s[1][r] * scale;
            const float v2 = s[2][r] * scale, v3 = s[3][r] * scale;
            float mx = fmaxf(fmaxf(v0, v1), fmaxf(v2, v3));
            mx = fmaxf(mx, __shfl_xor(mx, 1));
            mx = fmaxf(mx, __shfl_xor(mx, 2));
            mx = fmaxf(mx, __shfl_xor(mx, 4));
            mx = fmaxf(mx, __shfl_xor(mx, 8));
            const float mn = fmaxf(m_r[r], mx);
            p[0][r] = __expf(v0 - mn);
            p[1][r] = __expf(v1 - mn);
            p[2][r] = __expf(v2 - mn);
            p[3][r] = __expf(v3 - mn);
            float rs = (p[0][r] + p[1][r]) + (p[2][r] + p[3][r]);
            rs += __shfl_xor(rs, 1);
            rs += __shfl_xor(rs, 2);
            rs += __shfl_xor(rs, 4);
            rs += __shfl_xor(rs, 8);
            esc[r] = __expf(m_r[r] - mn);
            l_r[r] = l_r[r] * esc[r] + rs;
            m_r[r] = mn;
        }
#pragma unroll
        for (int j2 = 0; j2 < 8; j2++)
#pragma unroll
            for (int r = 0; r < 4; r++)
                oacc[j2][r] *= esc[r];
#pragma unroll
        for (int j = 0; j < 4; j++)
#pragma unroll
            for (int r = 0; r < 4; r++) {
                const int q = w * 16 + hi * 4 + r;
                const int cp = (j * 2 + (rc >> 3)) ^ (q & 7);
                Ps[q * 64 + cp * 8 + (rc & 7)] = __float2bfloat16(p[j][r]);
            }
        __syncthreads();
#pragma unroll
        for (int ks = 0; ks < 2; ks++) {
            const int sc = (ks * 4 + hi) ^ rlo;
            short8x ap = *(const short8x*)(Ps + (w * 16 + rc) * 64 + sc * 8);
#pragma unroll
            for (int j2 = 0; j2 < 8; j2++) {
                short8x bv = *(const short8x*)(Vs + (j2 * 16 + rc) * 64 + sc * 8);
                oacc[j2] = __builtin_amdgcn_mfma_f32_16x16x32_bf16(ap, bv, oacc[j2], 0, 0, 0);
            }
        }
    }

    float* ob = OP + (((long)sp * (cB * cL) + b * cL + qt * 32)) * cDM + h * cHD;
#pragma unroll
    for (int j2 = 0; j2 < 8; j2++)
#pragma unroll
        for (int r = 0; r < 4; r++)
            ob[(long)(w * 16 + hi * 4 + r) * cDM + j2 * 16 + rc] = oacc[j2][r];
    if (rc == 0) {
#pragma unroll
        for (int r = 0; r < 4; r++) {
            const int row = qt * 32 + w * 16 + hi * 4 + r;
            ML[(((long)sp * cB + b) * cH + h) * cL + row] = make_float2(m_r[r], l_r[r]);
        }
    }
}

// =====================================================================
// Combine flash splits (verified round 12).
// =====================================================================
__global__ __launch_bounds__(256)
void flash_combine_kernel(const float* __restrict__ OP, const float2* __restrict__ ML,
                          bf16* __restrict__ Op)
{
    const int row = blockIdx.x;        // 0..2047
    const int b = row >> 10, lr = row & 1023;
    const int t = threadIdx.x;
    __shared__ float ms[cSPL][cH], ls[cSPL][cH];
    __shared__ float wgt[cSPL][cH], linv[cH];
    if (t < cSPL * cH) {
        const int s = t >> 2, h = t & 3;
        float2 v = ML[(((long)s * cB + b) * cH + h) * cL + lr];
        ms[s][h] = v.x; ls[s][h] = v.y;
    }
    __syncthreads();
    if (t < cH) {
        const int h = t;
        float M = fmaxf(fmaxf(ms[0][h], ms[1][h]), fmaxf(ms[2][h], ms[3][h]));
        float L = 0.f;
#pragma unroll
        for (int s = 0; s < cSPL; s++) {
            const float e = __expf(ms[s][h] - M);
            wgt[s][h] = e;
            L += e * ls[s][h];
        }
        linv[h] = 1.f / L;
    }
    __syncthreads();
#pragma unroll
    for (int c0 = 0; c0 < 2; c0++) {
        const int col = t + c0 * 256;
        const int h = col >> 7;
        float o = 0.f;
#pragma unroll
        for (int s = 0; s < cSPL; s++)
            o += wgt[s][h] * OP[((long)s * (cB * cL) + row) * cDM + col];
        Op[(long)row * cDM + col] = __float2bfloat16(o * linv[h]);
    }
}

// =====================================================================
// split-K partial reduce:  out = sum_s parts[s]  (f32 + bf16 outputs)
// =====================================================================
__global__ void splitk_reduce_kernel(const float* __restrict__ parts, float* __restrict__ outf,
                                     bf16* __restrict__ outb, int n4, int sliceN4, int S)
{
    const int i = blockIdx.x * 256 + threadIdx.x;
    if (i >= n4) return;
    float4 a = ((const float4*)parts)[i];
    for (int s2 = 1; s2 < S; s2++) {
        float4 b2 = ((const float4*)parts)[i + (long)s2 * sliceN4];
        a.x += b2.x; a.y += b2.y; a.z += b2.z; a.w += b2.w;
    }
    ((float4*)outf)[i] = a;
    bf16 b0 = __float2bfloat16(a.x), b1 = __float2bfloat16(a.y);
    bf16 b2 = __float2bfloat16(a.z), b3 = __float2bfloat16(a.w);
    short4 pk = { *(short*)&b0, *(short*)&b1, *(short*)&b2, *(short*)&b3 };
    ((short4*)outb)[i] = pk;
}

// =====================================================================
// One-shot fused f32->bf16 conversion of all weight tensors + enc.
// =====================================================================
__global__ void cvt_all_kernel(
    const float* __restrict__ s0, bf16* __restrict__ d0,   // enc
    const float* __restrict__ s1, bf16* __restrict__ d1,   // m_in_w
    const float* __restrict__ s2, bf16* __restrict__ d2,   // m_xproj
    const float* __restrict__ s3, bf16* __restrict__ d3,   // m_dt_w
    const float* __restrict__ s4, bf16* __restrict__ d4,   // m_out_w
    const float* __restrict__ s5, bf16* __restrict__ d5,   // a_in_w
    const float* __restrict__ s6, bf16* __restrict__ d6,   // a_out_w
    const float* __restrict__ s7, bf16* __restrict__ d7)   // W_out
{
    constexpr long E0 = 1048576, E1 = 4194304, E2 = 262144, E3 = 131072;
    constexpr long E4 = 2097152, E5 = 3145728, E6 = 1048576, E7 = 40960;
    constexpr long C0 = E0, C1 = C0 + E1, C2 = C1 + E2, C3 = C2 + E3;
    constexpr long C4 = C3 + E4, C5 = C4 + E5, C6 = C5 + E6, C7 = C6 + E7;
    long i = ((long)blockIdx.x * 256 + threadIdx.x) * 4;
    if (i >= C7) return;
    const float* s; bf16* d;
    if      (i < C0) { s = s0; d = d0; }
    else if (i < C1) { s = s1; d = d1; i -= C0; }
    else if (i < C2) { s = s2; d = d2; i -= C1; }
    else if (i < C3) { s = s3; d = d3; i -= C2; }
    else if (i < C4) { s = s4; d = d4; i -= C3; }
    else if (i < C5) { s = s5; d = d5; i -= C4; }
    else if (i < C6) { s = s6; d = d6; i -= C5; }
    else             { s = s7; d = d7; i -= C6; }
    float4 v = *(const float4*)(s + i);
    d[i]     = __float2bfloat16(v.x);
    d[i + 1] = __float2bfloat16(v.y);
    d[i + 2] = __float2bfloat16(v.z);
    d[i + 3] = __float2bfloat16(v.w);
}

// f32 (rows x kin) -> bf16 (rows x kout), zero-padded beyond kin
__global__ void cvt_pad_kernel(const float* __restrict__ in, bf16* __restrict__ out,
                               int rows, int kin, int kout)
{
    const int idx = blockIdx.x * 256 + threadIdx.x;
    if (idx >= rows * kout) return;
    const int r = idx / kout, k = idx - r * kout;
    out[idx] = __float2bfloat16(k < kin ? in[(long)r * kin + k] : 0.f);
}

// =====================================================================
// bf16 transpose, batched over (layer, batch):  z = lay*cB + b.
// =====================================================================
__global__ void transpose_bf16_kernel(const bf16* __restrict__ in, bf16* __restrict__ out,
                                      int ldin, int col0, long inLS, long outLS)
{
    __shared__ bf16 t[32][33];
    const int z = blockIdx.z;
    const int lay = z >> 1, b = z & 1;
    in  += (long)lay * inLS;
    out += (long)lay * outLS;
    const int le0 = blockIdx.x * 32, d0 = blockIdx.y * 32;
    const int tid = threadIdx.x;
    const int c = tid & 31, r = tid >> 5;
    for (int i = r; i < 32; i += 8)
        t[i][c] = in[((long)b * cLE + le0 + i) * ldin + col0 + d0 + c];
    __syncthreads();
    for (int i = r; i < 32; i += 8)
        out[((long)b * cDM + d0 + i) * cLE + le0 + c] = t[c][i];
}

// =====================================================================
// RMSNorm per row — layer-0 entry
// =====================================================================
__global__ void rmsnorm_kernel(const float* __restrict__ x, const float* __restrict__ w,
                               float* __restrict__ outf, bf16* __restrict__ outb, int Dm)
{
    const int row = blockIdx.x;
    const float* xr = x + (long)row * Dm;
    float s = 0.f;
    for (int i = threadIdx.x; i < Dm; i += 256) { float v = xr[i]; s += v * v; }
    __shared__ float red[5];
    const int lane = threadIdx.x & 63, wv = threadIdx.x >> 6;
#pragma unroll
    for (int off = 1; off < 64; off <<= 1) s += __shfl_xor(s, off);
    if (lane == 0) red[wv] = s;
    __syncthreads();
    if (threadIdx.x == 0) {
        float t = red[0] + red[1] + red[2] + red[3];
        red[4] = rsqrtf(t / Dm + 1e-5f);
    }
    __syncthreads();
    const float scale = red[4];
    for (int i = threadIdx.x; i < Dm; i += 256) {
        float v = xr[i] * scale * w[i];
        if (outf) outf[(long)row * Dm + i] = v;
        if (outb) outb[(long)row * Dm + i] = __float2bfloat16(v);
    }
}

// =====================================================================
// LayerNorm per row (Dm=512, 2 elems/thread) + fused next-RMS.
// =====================================================================
__global__ void layernorm_kernel(const float* __restrict__ x, const float* __restrict__ w,
                                 const float* __restrict__ b, float* __restrict__ outf,
                                 bf16* __restrict__ outb,
                                 const float* __restrict__ rms_w, bf16* __restrict__ rms_out)
{
    const int row = blockIdx.x;
    const float* xr = x + (long)row * 512;
    const int t = threadIdx.x;
    const int i0 = t, i1 = t + 256;
    float x0 = xr[i0], x1 = xr[i1];
    float s = x0 + x1, sq = x0 * x0 + x1 * x1;
    __shared__ float red[8];
    __shared__ float mv[2];
    const int lane = t & 63, wv = t >> 6;
#pragma unroll
    for (int off = 1; off < 64; off <<= 1) { s += __shfl_xor(s, off); sq += __shfl_xor(sq, off); }
    if (lane == 0) { red[wv] = s; red[4 + wv] = sq; }
    __syncthreads();
    if (t == 0) {
        float ts = red[0] + red[1] + red[2] + red[3];
        float tq = red[4] + red[5] + red[6] + red[7];
        float m = ts / 512.f;
        float var = tq / 512.f - m * m;
        mv[0] = m;
        mv[1] = rsqrtf(var + 1e-5f);
    }
    __syncthreads();
    const float m = mv[0], rs = mv[1];
    const float v0 = (x0 - m) * rs * w[i0] + b[i0];
    const float v1 = (x1 - m) * rs * w[i1] + b[i1];
    outf[(long)row * 512 + i0] = v0;
    outf[(long)row * 512 + i1] = v1;
    outb[(long)row * 512 + i0] = __float2bfloat16(v0);
    outb[(long)row * 512 + i1] = __float2bfloat16(v1);
    float s2 = v0 * v0 + v1 * v1;
#pragma unroll
    for (int off = 1; off < 64; off <<= 1) s2 += __shfl_xor(s2, off);
    if (lane == 0) red[wv] = s2;
    __syncthreads();
    if (t == 0) mv[0] = rsqrtf((red[0] + red[1] + red[2] + red[3]) / 512.f + 1e-5f);
    __syncthreads();
    const float rsc = mv[0];
    rms_out[(long)row * 512 + i0] = __float2bfloat16(v0 * rsc * rms_w[i0]);
    rms_out[(long)row * 512 + i1] = __float2bfloat16(v1 * rsc * rms_w[i1]);
}

// =====================================================================
// Causal depthwise conv (K=4) + bias + SiLU -> xm f32 + bf16
// =====================================================================
__global__ void conv_silu_kernel(const float* __restrict__ xr, const float* __restrict__ w,
                                 const float* __restrict__ bias, float* __restrict__ xm,
                                 bf16* __restrict__ xmb)
{
    const int idx = blockIdx.x * 256 + threadIdx.x;
    if (idx >= cB * cL * cDI) return;
    const int d = idx & (cDI - 1);
    const int l = (idx >> 10) & (cL - 1);
    const int b = idx >> 20;
    float s = bias[d];
#pragma unroll
    for (int j = 0; j < cKC; j++) {
        const int ls = l + j - (cKC - 1);
        if (ls >= 0) s += w[d * cKC + j] * xr[((long)(b * cL + ls)) * (2 * cDI) + d];
    }
    s = s / (1.f + __expf(-s));
    xm[(long)idx] = s;
    xmb[(long)idx] = __float2bfloat16(s);
}

// =====================================================================
// Chunk-parallel selective scan, 4 states (n) per thread, NCH=64 chunks.
// (Reverted to 3-phase: d in thread-low bits keeps loads coalesced;
//  the fused 1-kernel variant put d in block idx -> 7x overfetch, −172us.)
// Thread mapping idx4 bits: ng[1:0], d[11:2], ch[17:12], b[18]
// =====================================================================
__global__ void scan_phase1(const float* __restrict__ xm, const float* __restrict__ delta,
                            const float* __restrict__ xdbl, const float* __restrict__ Alog,
                            float* __restrict__ aprod_out, float* __restrict__ send_out)
{
    const int idx4 = blockIdx.x * 256 + threadIdx.x;   // cB*cNCH*cDI*4
    const int ng = idx4 & 3;
    const int d  = (idx4 >> 2) & (cDI - 1);
    const int ch = (idx4 >> 12) & (cNCH - 1);
    const int b  = idx4 >> 18;
    const float4 Al = *(const float4*)(Alog + d * cDS + 4 * ng);
    const float A0 = -__expf(Al.x), A1 = -__expf(Al.y), A2 = -__expf(Al.z), A3 = -__expf(Al.w);
    float s0 = 0.f, s1 = 0.f, s2 = 0.f, s3 = 0.f;
    float p0 = 1.f, p1 = 1.f, p2 = 1.f, p3 = 1.f;
    const int l0 = ch * cCHL;
    const float* dp = delta + (long)(b * cL + l0) * cDI + d;
    const float* up = xm    + (long)(b * cL + l0) * cDI + d;
    const float* xb = xdbl  + (long)(b * cL + l0) * 64 + cDTR + 4 * ng;
#pragma unroll
    for (int t = 0; t < cCHL; t++) {
        const float dl = dp[(long)t * cDI];
        const float du = dl * up[(long)t * cDI];
        const float4 Bv = *(const float4*)(xb + (long)t * 64);
        const float a0 = __expf(dl * A0), a1 = __expf(dl * A1);
        const float a2 = __expf(dl * A2), a3 = __expf(dl * A3);
        s0 = a0 * s0 + du * Bv.x; p0 *= a0;
        s1 = a1 * s1 + du * Bv.y; p1 *= a1;
        s2 = a2 * s2 + du * Bv.z; p2 *= a2;
        s3 = a3 * s3 + du * Bv.w; p3 *= a3;
    }
    const long base4 = (((long)(b * cNCH + ch) * cDI + d) * cDS) + 4 * ng;
    float4 pv = { p0, p1, p2, p3 };
    float4 sv = { s0, s1, s2, s3 };
    *(float4*)(aprod_out + base4) = pv;
    *(float4*)(send_out + base4)  = sv;
}

__global__ void scan_phase2(const float* __restrict__ aprod, const float* __restrict__ send,
                            float* __restrict__ sinit)
{
    const int j = blockIdx.x * 64 + threadIdx.x;    // cB*cDI*cDS, 64-thr blocks
    const int n = j & (cDS - 1);
    const int d = (j >> 4) & (cDI - 1);
    const int b = j >> 14;
    float s = 0.f;
#pragma unroll
    for (int c = 0; c < cNCH; c++) {
        const long off = (((long)(b * cNCH + c) * cDI + d) * cDS) + n;
        sinit[off] = s;
        s = aprod[off] * s + send[off];
    }
}

__global__ void scan_phase3(const float* __restrict__ xm, const float* __restrict__ delta,
                            const float* __restrict__ xdbl, const float* __restrict__ Alog,
                            const float* __restrict__ Dv, const float* __restrict__ xr,
                            const float* __restrict__ sinit, bf16* __restrict__ y)
{
    const int idx4 = blockIdx.x * 256 + threadIdx.x;   // cB*cNCH*cDI*4
    const int ng = idx4 & 3;
    const int d  = (idx4 >> 2) & (cDI - 1);
    const int ch = (idx4 >> 12) & (cNCH - 1);
    const int b  = idx4 >> 18;
    const float4 Al = *(const float4*)(Alog + d * cDS + 4 * ng);
    const float A0 = -__expf(Al.x), A1 = -__expf(Al.y), A2 = -__expf(Al.z), A3 = -__expf(Al.w);
    const float Dval = Dv[d];
    const long base4 = (((long)(b * cNCH + ch) * cDI + d) * cDS) + 4 * ng;
    float4 st = *(const float4*)(sinit + base4);
    float s0 = st.x, s1 = st.y, s2 = st.z, s3 = st.w;
    const int l0 = ch * cCHL;
    const float* dp = delta + (long)(b * cL + l0) * cDI + d;
    const float* up = xm    + (long)(b * cL + l0) * cDI + d;
    const float* xb = xdbl  + (long)(b * cL + l0) * 64 + cDTR + 4 * ng;
    const float* xc = xb + cDS;
    const float* rp = xr + (long)(b * cL + l0) * (2 * cDI) + cDI + d;
    bf16* yp = y + (long)(b * cL + l0) * cDI + d;
#pragma unroll
    for (int t = 0; t < cCHL; t++) {
        const float dl = dp[(long)t * cDI];
        const float u  = up[(long)t * cDI];
        const float du = dl * u;
        const float4 Bv = *(const float4*)(xb + (long)t * 64);
        const float4 Cv = *(const float4*)(xc + (long)t * 64);
        const float a0 = __expf(dl * A0), a1 = __expf(dl * A1);
        const float a2 = __expf(dl * A2), a3 = __expf(dl * A3);
        s0 = a0 * s0 + du * Bv.x;
        s1 = a1 * s1 + du * Bv.y;
        s2 = a2 * s2 + du * Bv.z;
        s3 = a3 * s3 + du * Bv.w;
        float c = s0 * Cv.x;
        c = fmaf(s1, Cv.y, c);
        c = fmaf(s2, Cv.z, c);
        c = fmaf(s3, Cv.w, c);
        c += __shfl_xor(c, 1);
        c += __shfl_xor(c, 2);
        if (ng == 0) {
            const float res = rp[(long)t * 2 * cDI];
            const float sig = 1.f / (1.f + __expf(-res));
            yp[(long)t * cDI] = __float2bfloat16((c + u * Dval) * (res * sig));
        }
    }
}

// =====================================================================
extern "C" void kernel_launch(void* const* d_in, const int* in_sizes, int n_in,
                              void* d_out, int out_size, void* d_ws, size_t ws_size,
                              hipStream_t stream)
{
    const float* x       = (const float*)d_in[0];
    const float* enc     = (const float*)d_in[1];
    const float* W_in    = (const float*)d_in[2];
    const float* b_in    = (const float*)d_in[3];
    const float* m_norm_w= (const float*)d_in[4];
    const float* m_in_w  = (const float*)d_in[5];
    const float* m_conv_w= (const float*)d_in[6];
    const float* m_conv_b= (const float*)d_in[7];
    const float* m_xproj = (const float*)d_in[8];
    const float* m_dt_w  = (const float*)d_in[9];
    const float* m_dt_b  = (const float*)d_in[10];
    const float* m_Alog  = (const float*)d_in[11];
    const float* m_D     = (const float*)d_in[12];
    const float* m_out_w = (const float*)d_in[13];
    const float* a_in_w  = (const float*)d_in[14];
    const float* a_in_b  = (const float*)d_in[15];
    const float* a_out_w = (const float*)d_in[16];
    const float* a_out_b = (const float*)d_in[17];
    const float* a_ln_w  = (const float*)d_in[18];
    const float* a_ln_b  = (const float*)d_in[19];
    const float* normf_w = (const float*)d_in[20];
    const float* W_out   = (const float*)d_in[21];
    float* out = (float*)d_out;

    float* ws = (float*)d_ws;
    long off = 0;
    auto allocf = [&](long n) { float* p = ws + off; off += n; return p; };

    const long M1 = 1 << 20;
    float* bufH    = allocf(M1);
    float* bufPre  = allocf(M1);         // also xproj split-K partials
    float* bufXR   = allocf(4 * M1);
    float* bufXM   = allocf(2 * M1);
    float* bufDelta= allocf(2 * M1);
    float* bufXDBL = allocf(M1 / 8);
    bf16* bufU    = (bf16*)allocf(M1 / 2);      // 2048x512 bf16 (rms output)
    bf16* bufHb   = (bf16*)allocf(M1 / 2);
    bf16* bufXMb  = (bf16*)allocf(M1);          // 2048x1024 bf16
    bf16* bufXDBLb= (bf16*)allocf(M1 / 16);
    bf16* bufY    = (bf16*)allocf(M1);          // 2048x1024 bf16
    bf16* bufQ    = (bf16*)allocf(M1 / 2);
    bf16* bufO    = (bf16*)allocf(M1 / 2);
    bf16* encb    = (bf16*)allocf(M1 / 2);
    bf16* w_in_b  = (bf16*)allocf(2 * M1);
    bf16* w_xp_b  = (bf16*)allocf(M1 / 8);
    bf16* w_dt_b  = (bf16*)allocf(M1 / 16);
    bf16* w_out_b = (bf16*)allocf(M1);
    bf16* w_ain_b = (bf16*)allocf(3 * M1 / 2);
    bf16* w_aout_b= (bf16*)allocf(M1 / 2);
    bf16* x_pad   = (bf16*)allocf(2048L * 96 / 2);
    bf16* w_inp_b = (bf16*)allocf(512L * 96 / 2);
    bf16* w_outf_b= (bf16*)allocf(80L * 512 / 2);
    float* bufAP  = allocf(2 * M1);
    float* bufSE  = allocf(2 * M1);
    float* bufSI  = allocf(2 * M1);
    bf16* bufKV4  = (bf16*)allocf(4 * M1);      // 4 layers x 2M bf16
    bf16* bufVT4  = (bf16*)allocf(2 * M1);      // 4 layers x 1M bf16
    float* bufOP  = allocf(4 * M1);             // flash partials [4][2048][512] f32
    float2* bufML = (float2*)allocf(M1 / 16);   // [4][2][4][1024] float2

    const int Mrows = cB * cL;   // 2048
    const long SUMSZ4 = (long)cB * cNCH * cDI * 4;   // 524288
    const long kvLS = (long)Mrows * 2 * cDM;
    const long vtLS = (long)cB * cDM * cLE;

    // ---- one-time conversions ----
    cvt_all_kernel<<<11688, 256, 0, stream>>>(
        enc, encb, m_in_w, w_in_b, m_xproj, w_xp_b, m_dt_w, w_dt_b,
        m_out_w, w_out_b, a_in_w, w_ain_b, a_out_w, w_aout_b, W_out, w_outf_b);
    cvt_pad_kernel<<<(Mrows * 96 + 255) / 256, 256, 0, stream>>>(x, x_pad, Mrows, cNM, 96);
    cvt_pad_kernel<<<(cDM * 96 + 255) / 256, 256, 0, stream>>>(W_in, w_inp_b, cDM, cNM, 96);

    // ---- all-layer K|V projection + V^T ----
    bgemm(0, 64, 128, encb, w_ain_b + (long)cDM * cDM, a_in_b + cDM, nullptr, nullptr, bufKV4,
          Mrows, 2 * cDM, cDM, cDM, cDM, 0, 2 * cDM, 0,
          cLAYERS, 1,
          0, 0,
          (long)3 * cDM * cDM, 0,
          0, 0, kvLS, 0,
          (long)3 * cDM,
          stream);
    {
        dim3 g(cLE / 32, cDM / 32, cLAYERS * cB);
        transpose_bf16_kernel<<<g, 256, 0, stream>>>(bufKV4, bufVT4, 2 * cDM, cDM, kvLS, vtLS);
    }

    // h = x @ W_in.T + b_in ; layer-0 rmsnorm -> bufU
    bgemm_plain(0, 64, 64, x_pad, w_inp_b, b_in, nullptr, bufH, nullptr,
                Mrows, cDM, 96, 96, 96, cDM, 0, 0, stream);
    rmsnorm_kernel<<<Mrows, 256, 0, stream>>>(bufH, m_norm_w, nullptr, bufU, cDM);

    for (int i = 0; i < cLAYERS; i++) {
        const bf16*  in_w   = w_in_b   + (long)i * 2 * cDI * cDM;
        const float* conv_w = m_conv_w + (long)i * cDI * cKC;
        const float* conv_b = m_conv_b + (long)i * cDI;
        const bf16*  xproj  = w_xp_b   + (long)i * 64 * cDI;
        const bf16*  dt_w   = w_dt_b   + (long)i * cDI * cDTR;
        const float* dt_b   = m_dt_b   + (long)i * cDI;
        const float* Alog   = m_Alog   + (long)i * cDI * cDS;
        const float* Dv     = m_D      + (long)i * cDI;
        const bf16*  out_w  = w_out_b  + (long)i * cDM * cDI;
        const bf16*  ain_w  = w_ain_b  + (long)i * 3 * cDM * cDM;
        const float* ain_b  = a_in_b   + (long)i * 3 * cDM;
        const bf16*  aout_w = w_aout_b + (long)i * cDM * cDM;
        const float* aout_b = a_out_b  + (long)i * cDM;
        const float* ln_w   = a_ln_w   + (long)i * cDM;
        const float* ln_b   = a_ln_b   + (long)i * cDM;
        const bf16*  kv_l   = bufKV4 + (long)i * kvLS;
        const bf16*  vt_l   = bufVT4 + (long)i * vtLS;
        const float* next_rms_w = (i + 1 < cLAYERS) ? (m_norm_w + (long)(i + 1) * cDM) : normf_w;

        // ---- mamba (bufU holds rmsnorm(h) bf16) ----
        bgemm_plain(0, 64, 128, bufU, in_w, nullptr, nullptr, bufXR, nullptr,
                    Mrows, 2 * cDI, cDM, cDM, cDM, 2 * cDI, 0, 0, stream);
        conv_silu_kernel<<<(cB * cL * cDI) / 256, 256, 0, stream>>>(bufXR, conv_w, conv_b, bufXM, bufXMb);
        bgemm(0, 64, 64, bufXMb, xproj, nullptr, nullptr, bufPre, nullptr,
              Mrows, 64, cDI / 8, cDI, cDI, 64, 0, 0,
              8, 1, 128, 0, 128, 0, (long)Mrows * 64, 0, 0, 0, 0, stream);
        splitk_reduce_kernel<<<(Mrows * 64 / 4 + 255) / 256, 256, 0, stream>>>(
            bufPre, bufXDBL, bufXDBLb, Mrows * 64 / 4, Mrows * 64 / 4, 8);
        bgemm_plain(1, 64, 128, bufXDBLb, dt_w, dt_b, nullptr, bufDelta, nullptr,
                    Mrows, cDI, cDTR, 64, cDTR, cDI, 0, 0, stream);
        scan_phase1<<<(int)(SUMSZ4 / 256), 256, 0, stream>>>(bufXM, bufDelta, bufXDBL, Alog, bufAP, bufSE);
        scan_phase2<<<(cB * cDI * cDS) / 64, 64, 0, stream>>>(bufAP, bufSE, bufSI);
        scan_phase3<<<(int)(SUMSZ4 / 256), 256, 0, stream>>>(bufXM, bufDelta, bufXDBL, Alog, Dv, bufXR, bufSI, bufY);
        bgemm_plain(0, 64, 64, bufY, out_w, nullptr, bufH, bufH, bufHb,
                    Mrows, cDM, cDI, cDI, cDI, cDM, cDM, cDM, stream);

        // ---- cross attention: Q gemm -> split flash -> combine ----
        bgemm_plain(0, 64, 64, bufHb, ain_w, ain_b, nullptr, nullptr, bufQ,
                    Mrows, cDM, cDM, cDM, cDM, 0, cDM, 0, stream);
        {
            dim3 g(cL / 32, cB * cH, cSPL);
            flash_split_kernel<<<g, 128, 0, stream>>>(bufQ, kv_l, vt_l, bufOP, bufML,
                                                      0.08838834764831845f);
        }
        flash_combine_kernel<<<Mrows, 256, 0, stream>>>(bufOP, bufML, bufO);
        // pre = o @ aout_w.T + aout_b + h ; h = LN(pre) (+ fused next-RMS -> bufU)
        bgemm_plain(0, 64, 64, bufO, aout_w, aout_b, bufH, bufPre, nullptr,
                    Mrows, cDM, cDM, cDM, cDM, cDM, 0, cDM, stream);
        layernorm_kernel<<<Mrows, 256, 0, stream>>>(bufPre, ln_w, ln_b, bufH, bufHb,
                                                    next_rms_w, bufU);
    }

    // final: out = bufU(= rms(h, normf_w)) @ W_out.T
    bgemm_plain(0, 64, 64, bufU, w_outf_b, nullptr, nullptr, out, nullptr,
                Mrows, cNM, cDM, cDM, cDM, cNM, 0, 0, stream);
}

// Round 15
// 712.884 us; speedup vs baseline: 1.2796x; 1.0418x over previous
//
#include <hip/hip_runtime.h>
#include <hip/hip_bf16.h>
#include <math.h>

typedef __hip_bfloat16 bf16;
typedef __attribute__((ext_vector_type(8))) short short8x;
typedef __attribute__((ext_vector_type(4))) float f32x4;

// ---- problem constants ----
static constexpr int cB   = 2;
static constexpr int cL   = 1024;
static constexpr int cLE  = 1024;
static constexpr int cNM  = 80;
static constexpr int cDM  = 512;
static constexpr int cLAYERS = 4;
static constexpr int cDS  = 16;
static constexpr int cKC  = 4;     // conv taps
static constexpr int cH   = 4;     // heads
static constexpr int cDI  = 1024;  // EXP*DM
static constexpr int cDTR = 32;
static constexpr int cHD  = 128;   // head dim

static constexpr int cNCH = 64;    // scan chunks (bit extraction assumes 64)
static constexpr int cCHL = cL / cNCH;  // 16 steps per chunk
static constexpr int cSPL = 4;     // flash KV splits

#define GLL16(g, l) __builtin_amdgcn_global_load_lds( \
    (const __attribute__((address_space(1))) void*)(g), \
    (__attribute__((address_space(3))) void*)(l), 16, 0, 0)

// =====================================================================
// bf16 MFMA GEMM, BMxBN tile, 4 waves (2x2), K-step 32.
// =====================================================================
template<int ACT, int BM, int BN>
__global__ __launch_bounds__(256)
void bgemm_kernel(const bf16* __restrict__ A, const bf16* __restrict__ W,
                  const float* __restrict__ bias, const float* __restrict__ addv,
                  float* __restrict__ Cf, bf16* __restrict__ Cb,
                  int M, int N, int Kd, int lda, int ldw, int ldcf, int ldcb, int ldadd,
                  int bdiv, long sA1, long sA2, long sW1, long sW2,
                  long sCf1, long sCf2, long sCb1, long sCb2, long sBias)
{
    constexpr int RM = BM / 32;
    constexpr int RN = BN / 32;
    const int z = blockIdx.z;
    const int i1 = z / bdiv, i2 = z % bdiv;
    A += i1 * sA1 + i2 * sA2;
    W += i1 * sW1 + i2 * sW2;
    if (bias) bias += i1 * sBias;

    const int bm = blockIdx.y * BM;
    const int bn = blockIdx.x * BN;
    const int tid = threadIdx.x;
    const int lane = tid & 63;
    const int wid = tid >> 6;
    const int wr = wid >> 1, wc = wid & 1;

    __shared__ bf16 As[BM * 32];
    __shared__ bf16 Bs[BN * 32];

    f32x4 acc[RM][RN] = {};

    const int r_in = lane >> 2;
    const int kb   = (lane & 3) * 8;
    const int hi   = lane >> 4;
    const int rc   = lane & 15;

    for (int k0 = 0; k0 < Kd; k0 += 32) {
#pragma unroll
        for (int iss = 0; iss < BM / 64; iss++) {
            const int row = wid * (BM / 4) + iss * 16 + r_in;
            int gm = bm + row; if (gm >= M) gm = M - 1;
            const bf16* ga = A + (long)gm * lda + k0 + kb;
            GLL16(ga, As + (wid * (BM / 4) + iss * 16) * 32);
        }
#pragma unroll
        for (int iss = 0; iss < BN / 64; iss++) {
            const int row = wid * (BN / 4) + iss * 16 + r_in;
            int gn = bn + row; if (gn >= N) gn = N - 1;
            const bf16* gb = W + (long)gn * ldw + k0 + kb;
            GLL16(gb, Bs + (wid * (BN / 4) + iss * 16) * 32);
        }
        asm volatile("s_waitcnt vmcnt(0)" ::: "memory");
        __syncthreads();

        short8x af[RM], bfv[RN];
#pragma unroll
        for (int i = 0; i < RM; i++)
            af[i] = *(const short8x*)(As + (wr * (BM / 2) + i * 16 + rc) * 32 + hi * 8);
#pragma unroll
        for (int j = 0; j < RN; j++)
            bfv[j] = *(const short8x*)(Bs + (wc * (BN / 2) + j * 16 + rc) * 32 + hi * 8);
#pragma unroll
        for (int i = 0; i < RM; i++)
#pragma unroll
            for (int j = 0; j < RN; j++)
                acc[i][j] = __builtin_amdgcn_mfma_f32_16x16x32_bf16(af[i], bfv[j], acc[i][j], 0, 0, 0);
        __syncthreads();
    }

    const long cfo = i1 * sCf1 + i2 * sCf2;
    const long cbo = i1 * sCb1 + i2 * sCb2;
#pragma unroll
    for (int i = 0; i < RM; i++) {
#pragma unroll
        for (int r = 0; r < 4; r++) {
            const int gm = bm + wr * (BM / 2) + i * 16 + hi * 4 + r;
            if (gm >= M) continue;
#pragma unroll
            for (int j = 0; j < RN; j++) {
                const int gn = bn + wc * (BN / 2) + j * 16 + rc;
                if (gn >= N) continue;
                float v = acc[i][j][r];
                if (bias) v += bias[gn];
                if (ACT == 1) v = (v > 20.f) ? v : log1pf(__expf(v));
                if (addv) v += addv[cfo + (long)gm * ldadd + gn];
                if (Cf) Cf[cfo + (long)gm * ldcf + gn] = v;
                if (Cb) Cb[cbo + (long)gm * ldcb + gn] = __float2bfloat16(v);
            }
        }
    }
}

static inline void bgemm(int ACT, int BM, int BN, const bf16* A, const bf16* W, const float* bias,
                         const float* addv, float* Cf, bf16* Cb,
                         int M, int N, int Kd, int lda, int ldw, int ldcf, int ldcb, int ldadd,
                         int nz, int bdiv, long sA1, long sA2, long sW1, long sW2,
                         long sCf1, long sCf2, long sCb1, long sCb2, long sBias, hipStream_t s)
{
    dim3 g((N + BN - 1) / BN, (M + BM - 1) / BM, nz), b(256);
#define BG_ARGS A, W, bias, addv, Cf, Cb, M, N, Kd, lda, ldw, ldcf, ldcb, ldadd, \
                bdiv, sA1, sA2, sW1, sW2, sCf1, sCf2, sCb1, sCb2, sBias
    if (BM == 128) {
        if (ACT == 1) bgemm_kernel<1, 128, 128><<<g, b, 0, s>>>(BG_ARGS);
        else          bgemm_kernel<0, 128, 128><<<g, b, 0, s>>>(BG_ARGS);
    } else if (BN == 128) {
        if (ACT == 1) bgemm_kernel<1, 64, 128><<<g, b, 0, s>>>(BG_ARGS);
        else          bgemm_kernel<0, 64, 128><<<g, b, 0, s>>>(BG_ARGS);
    } else {
        bgemm_kernel<0, 64, 64><<<g, b, 0, s>>>(BG_ARGS);
    }
#undef BG_ARGS
}

static inline void bgemm_plain(int ACT, int BM, int BN, const bf16* A, const bf16* W,
                               const float* bias, const float* addv, float* Cf, bf16* Cb,
                               int M, int N, int Kd, int lda, int ldw, int ldcf, int ldcb,
                               int ldadd, hipStream_t s)
{
    bgemm(ACT, BM, BN, A, W, bias, addv, Cf, Cb, M, N, Kd, lda, ldw, ldcf, ldcb, ldadd,
          1, 1, 0, 0, 0, 0, 0, 0, 0, 0, 0, s);
}

// =====================================================================
// Flash cross-attention, KV-split (verified round 12).
// =====================================================================
__global__ __launch_bounds__(128)
void flash_split_kernel(const bf16* __restrict__ Qp, const bf16* __restrict__ Kp,
                        const bf16* __restrict__ VTp, float* __restrict__ OP,
                        float2* __restrict__ ML, float scale)
{
    const int qt = blockIdx.x;            // 0..31
    const int bh = blockIdx.y;            // b*H + h
    const int sp = blockIdx.z;            // 0..3
    const int b = bh >> 2, h = bh & 3;
    const int tid = threadIdx.x;
    const int w = tid >> 6;               // 0..1
    const int lane = tid & 63;
    const int rc = lane & 15, hi = lane >> 4;
    const int rlo = rc & 7;

    __shared__ bf16 Ks[64 * 128];
    __shared__ bf16 Vs[128 * 64];
    __shared__ bf16 Ps[32 * 64];

    {
        const bf16* qb = Qp + ((long)(b * cL + qt * 32)) * cDM + h * cHD;
#pragma unroll
        for (int c = 0; c < 4; c++) {
            const int row = w * 16 + c * 4 + (lane >> 4);
            const int gc = (lane & 15) ^ (row & 7);
            GLL16(qb + (long)row * cDM + gc * 8, Ks + (w * 16 + c * 4) * 128);
        }
    }
    asm volatile("s_waitcnt vmcnt(0)" ::: "memory");
    __syncthreads();
    short8x aq[4];
#pragma unroll
    for (int kk = 0; kk < 4; kk++) {
        const int sc = (kk * 4 + hi) ^ rlo;
        aq[kk] = *(const short8x*)(Ks + (w * 16 + rc) * 128 + sc * 8);
    }
    __syncthreads();   // Ks free for K tiles

    float m_r[4], l_r[4];
#pragma unroll
    for (int r = 0; r < 4; r++) { m_r[r] = -1e30f; l_r[r] = 0.f; }
    f32x4 oacc[8] = {};

    const bf16* kb0 = Kp + ((long)(b * cLE)) * (2 * cDM) + h * cHD;
    const bf16* vb0 = VTp + ((long)(b * cDM + h * cHD)) * cLE;

    for (int t = 0; t < 4; t++) {
        const int kt = sp * 4 + t;
        __syncthreads();
#pragma unroll
        for (int c = 0; c < 8; c++) {
            const int row = w * 32 + c * 4 + (lane >> 4);
            const int gc = (lane & 15) ^ (row & 7);
            GLL16(kb0 + ((long)(kt * 64 + row)) * (2 * cDM) + gc * 8,
                  Ks + (w * 32 + c * 4) * 128);
        }
#pragma unroll
        for (int c = 0; c < 8; c++) {
            const int row = w * 64 + c * 8 + (lane >> 3);
            const int gc = (lane & 7) ^ (row & 7);
            GLL16(vb0 + (long)row * cLE + kt * 64 + gc * 8,
                  Vs + (w * 64 + c * 8) * 64);
        }
        asm volatile("s_waitcnt vmcnt(0)" ::: "memory");
        __syncthreads();

        f32x4 s[4] = {};
#pragma unroll
        for (int kk = 0; kk < 4; kk++) {
            const int sc = (kk * 4 + hi) ^ rlo;
#pragma unroll
            for (int j = 0; j < 4; j++) {
                short8x bk = *(const short8x*)(Ks + (j * 16 + rc) * 128 + sc * 8);
                s[j] = __builtin_amdgcn_mfma_f32_16x16x32_bf16(aq[kk], bk, s[j], 0, 0, 0);
            }
        }

        float p[4][4];
        float esc[4];
#pragma unroll
        for (int r = 0; r < 4; r++) {
            const float v0 = s[0][r] * scale, v1 = s[1][r] * scale;
            const float v2 = s[2][r] * scale, v3 = s[3][r] * scale;
            float mx = fmaxf(fmaxf(v0, v1), fmaxf(v2, v3));
            mx = fmaxf(mx, __shfl_xor(mx, 1));
            mx = fmaxf(mx, __shfl_xor(mx, 2));
            mx = fmaxf(mx, __shfl_xor(mx, 4));
            mx = fmaxf(mx, __shfl_xor(mx, 8));
            const float mn = fmaxf(m_r[r], mx);
            p[0][r] = __expf(v0 - mn);
            p[1][r] = __expf(v1 - mn);
            p[2][r] = __expf(v2 - mn);
            p[3][r] = __expf(v3 - mn);
            float rs = (p[0][r] + p[1][r]) + (p[2][r] + p[3][r]);
            rs += __shfl_xor(rs, 1);
            rs += __shfl_xor(rs, 2);
            rs += __shfl_xor(rs, 4);
            rs += __shfl_xor(rs, 8);
            esc[r] = __expf(m_r[r] - mn);
            l_r[r] = l_r[r] * esc[r] + rs;
            m_r[r] = mn;
        }
#pragma unroll
        for (int j2 = 0; j2 < 8; j2++)
#pragma unroll
            for (int r = 0; r < 4; r++)
                oacc[j2][r] *= esc[r];
#pragma unroll
        for (int j = 0; j < 4; j++)
#pragma unroll
            for (int r = 0; r < 4; r++) {
                const int q = w * 16 + hi * 4 + r;
                const int cp = (j * 2 + (rc >> 3)) ^ (q & 7);
                Ps[q * 64 + cp * 8 + (rc & 7)] = __float2bfloat16(p[j][r]);
            }
        __syncthreads();
#pragma unroll
        for (int ks = 0; ks < 2; ks++) {
            const int sc = (ks * 4 + hi) ^ rlo;
            short8x ap = *(const short8x*)(Ps + (w * 16 + rc) * 64 + sc * 8);
#pragma unroll
            for (int j2 = 0; j2 < 8; j2++) {
                short8x bv = *(const short8x*)(Vs + (j2 * 16 + rc) * 64 + sc * 8);
                oacc[j2] = __builtin_amdgcn_mfma_f32_16x16x32_bf16(ap, bv, oacc[j2], 0, 0, 0);
            }
        }
    }

    float* ob = OP + (((long)sp * (cB * cL) + b * cL + qt * 32)) * cDM + h * cHD;
#pragma unroll
    for (int j2 = 0; j2 < 8; j2++)
#pragma unroll
        for (int r = 0; r < 4; r++)
            ob[(long)(w * 16 + hi * 4 + r) * cDM + j2 * 16 + rc] = oacc[j2][r];
    if (rc == 0) {
#pragma unroll
        for (int r = 0; r < 4; r++) {
            const int row = qt * 32 + w * 16 + hi * 4 + r;
            ML[(((long)sp * cB + b) * cH + h) * cL + row] = make_float2(m_r[r], l_r[r]);
        }
    }
}

// =====================================================================
// Combine flash splits (verified round 12).
// =====================================================================
__global__ __launch_bounds__(256)
void flash_combine_kernel(const float* __restrict__ OP, const float2* __restrict__ ML,
                          bf16* __restrict__ Op)
{
    const int row = blockIdx.x;        // 0..2047
    const int b = row >> 10, lr = row & 1023;
    const int t = threadIdx.x;
    __shared__ float ms[cSPL][cH], ls[cSPL][cH];
    __shared__ float wgt[cSPL][cH], linv[cH];
    if (t < cSPL * cH) {
        const int s = t >> 2, h = t & 3;
        float2 v = ML[(((long)s * cB + b) * cH + h) * cL + lr];
        ms[s][h] = v.x; ls[s][h] = v.y;
    }
    __syncthreads();
    if (t < cH) {
        const int h = t;
        float M = fmaxf(fmaxf(ms[0][h], ms[1][h]), fmaxf(ms[2][h], ms[3][h]));
        float L = 0.f;
#pragma unroll
        for (int s = 0; s < cSPL; s++) {
            const float e = __expf(ms[s][h] - M);
            wgt[s][h] = e;
            L += e * ls[s][h];
        }
        linv[h] = 1.f / L;
    }
    __syncthreads();
#pragma unroll
    for (int c0 = 0; c0 < 2; c0++) {
        const int col = t + c0 * 256;
        const int h = col >> 7;
        float o = 0.f;
#pragma unroll
        for (int s = 0; s < cSPL; s++)
            o += wgt[s][h] * OP[((long)s * (cB * cL) + row) * cDM + col];
        Op[(long)row * cDM + col] = __float2bfloat16(o * linv[h]);
    }
}

// =====================================================================
// split-K partial reduce:  out = sum_s parts[s]  (f32 + bf16 outputs)
// =====================================================================
__global__ void splitk_reduce_kernel(const float* __restrict__ parts, float* __restrict__ outf,
                                     bf16* __restrict__ outb, int n4, int sliceN4, int S)
{
    const int i = blockIdx.x * 256 + threadIdx.x;
    if (i >= n4) return;
    float4 a = ((const float4*)parts)[i];
    for (int s2 = 1; s2 < S; s2++) {
        float4 b2 = ((const float4*)parts)[i + (long)s2 * sliceN4];
        a.x += b2.x; a.y += b2.y; a.z += b2.z; a.w += b2.w;
    }
    ((float4*)outf)[i] = a;
    bf16 b0 = __float2bfloat16(a.x), b1 = __float2bfloat16(a.y);
    bf16 b2 = __float2bfloat16(a.z), b3 = __float2bfloat16(a.w);
    short4 pk = { *(short*)&b0, *(short*)&b1, *(short*)&b2, *(short*)&b3 };
    ((short4*)outb)[i] = pk;
}

// =====================================================================
// One-shot fused f32->bf16 conversion of all weight tensors + enc.
// =====================================================================
__global__ void cvt_all_kernel(
    const float* __restrict__ s0, bf16* __restrict__ d0,   // enc
    const float* __restrict__ s1, bf16* __restrict__ d1,   // m_in_w
    const float* __restrict__ s2, bf16* __restrict__ d2,   // m_xproj
    const float* __restrict__ s3, bf16* __restrict__ d3,   // m_dt_w
    const float* __restrict__ s4, bf16* __restrict__ d4,   // m_out_w
    const float* __restrict__ s5, bf16* __restrict__ d5,   // a_in_w
    const float* __restrict__ s6, bf16* __restrict__ d6,   // a_out_w
    const float* __restrict__ s7, bf16* __restrict__ d7)   // W_out
{
    constexpr long E0 = 1048576, E1 = 4194304, E2 = 262144, E3 = 131072;
    constexpr long E4 = 2097152, E5 = 3145728, E6 = 1048576, E7 = 40960;
    constexpr long C0 = E0, C1 = C0 + E1, C2 = C1 + E2, C3 = C2 + E3;
    constexpr long C4 = C3 + E4, C5 = C4 + E5, C6 = C5 + E6, C7 = C6 + E7;
    long i = ((long)blockIdx.x * 256 + threadIdx.x) * 4;
    if (i >= C7) return;
    const float* s; bf16* d;
    if      (i < C0) { s = s0; d = d0; }
    else if (i < C1) { s = s1; d = d1; i -= C0; }
    else if (i < C2) { s = s2; d = d2; i -= C1; }
    else if (i < C3) { s = s3; d = d3; i -= C2; }
    else if (i < C4) { s = s4; d = d4; i -= C3; }
    else if (i < C5) { s = s5; d = d5; i -= C4; }
    else if (i < C6) { s = s6; d = d6; i -= C5; }
    else             { s = s7; d = d7; i -= C6; }
    float4 v = *(const float4*)(s + i);
    d[i]     = __float2bfloat16(v.x);
    d[i + 1] = __float2bfloat16(v.y);
    d[i + 2] = __float2bfloat16(v.z);
    d[i + 3] = __float2bfloat16(v.w);
}

// f32 (rows x kin) -> bf16 (rows x kout), zero-padded beyond kin
__global__ void cvt_pad_kernel(const float* __restrict__ in, bf16* __restrict__ out,
                               int rows, int kin, int kout)
{
    const int idx = blockIdx.x * 256 + threadIdx.x;
    if (idx >= rows * kout) return;
    const int r = idx / kout, k = idx - r * kout;
    out[idx] = __float2bfloat16(k < kin ? in[(long)r * kin + k] : 0.f);
}

// =====================================================================
// bf16 transpose, batched over (layer, batch):  z = lay*cB + b.
// =====================================================================
__global__ void transpose_bf16_kernel(const bf16* __restrict__ in, bf16* __restrict__ out,
                                      int ldin, int col0, long inLS, long outLS)
{
    __shared__ bf16 t[32][33];
    const int z = blockIdx.z;
    const int lay = z >> 1, b = z & 1;
    in  += (long)lay * inLS;
    out += (long)lay * outLS;
    const int le0 = blockIdx.x * 32, d0 = blockIdx.y * 32;
    const int tid = threadIdx.x;
    const int c = tid & 31, r = tid >> 5;
    for (int i = r; i < 32; i += 8)
        t[i][c] = in[((long)b * cLE + le0 + i) * ldin + col0 + d0 + c];
    __syncthreads();
    for (int i = r; i < 32; i += 8)
        out[((long)b * cDM + d0 + i) * cLE + le0 + c] = t[c][i];
}

// =====================================================================
// RMSNorm per row — layer-0 entry
// =====================================================================
__global__ void rmsnorm_kernel(const float* __restrict__ x, const float* __restrict__ w,
                               float* __restrict__ outf, bf16* __restrict__ outb, int Dm)
{
    const int row = blockIdx.x;
    const float* xr = x + (long)row * Dm;
    float s = 0.f;
    for (int i = threadIdx.x; i < Dm; i += 256) { float v = xr[i]; s += v * v; }
    __shared__ float red[5];
    const int lane = threadIdx.x & 63, wv = threadIdx.x >> 6;
#pragma unroll
    for (int off = 1; off < 64; off <<= 1) s += __shfl_xor(s, off);
    if (lane == 0) red[wv] = s;
    __syncthreads();
    if (threadIdx.x == 0) {
        float t = red[0] + red[1] + red[2] + red[3];
        red[4] = rsqrtf(t / Dm + 1e-5f);
    }
    __syncthreads();
    const float scale = red[4];
    for (int i = threadIdx.x; i < Dm; i += 256) {
        float v = xr[i] * scale * w[i];
        if (outf) outf[(long)row * Dm + i] = v;
        if (outb) outb[(long)row * Dm + i] = __float2bfloat16(v);
    }
}

// =====================================================================
// LayerNorm per row (Dm=512, 2 elems/thread) + fused next-RMS.
// =====================================================================
__global__ void layernorm_kernel(const float* __restrict__ x, const float* __restrict__ w,
                                 const float* __restrict__ b, float* __restrict__ outf,
                                 bf16* __restrict__ outb,
                                 const float* __restrict__ rms_w, bf16* __restrict__ rms_out)
{
    const int row = blockIdx.x;
    const float* xr = x + (long)row * 512;
    const int t = threadIdx.x;
    const int i0 = t, i1 = t + 256;
    float x0 = xr[i0], x1 = xr[i1];
    float s = x0 + x1, sq = x0 * x0 + x1 * x1;
    __shared__ float red[8];
    __shared__ float mv[2];
    const int lane = t & 63, wv = t >> 6;
#pragma unroll
    for (int off = 1; off < 64; off <<= 1) { s += __shfl_xor(s, off); sq += __shfl_xor(sq, off); }
    if (lane == 0) { red[wv] = s; red[4 + wv] = sq; }
    __syncthreads();
    if (t == 0) {
        float ts = red[0] + red[1] + red[2] + red[3];
        float tq = red[4] + red[5] + red[6] + red[7];
        float m = ts / 512.f;
        float var = tq / 512.f - m * m;
        mv[0] = m;
        mv[1] = rsqrtf(var + 1e-5f);
    }
    __syncthreads();
    const float m = mv[0], rs = mv[1];
    const float v0 = (x0 - m) * rs * w[i0] + b[i0];
    const float v1 = (x1 - m) * rs * w[i1] + b[i1];
    outf[(long)row * 512 + i0] = v0;
    outf[(long)row * 512 + i1] = v1;
    outb[(long)row * 512 + i0] = __float2bfloat16(v0);
    outb[(long)row * 512 + i1] = __float2bfloat16(v1);
    float s2 = v0 * v0 + v1 * v1;
#pragma unroll
    for (int off = 1; off < 64; off <<= 1) s2 += __shfl_xor(s2, off);
    if (lane == 0) red[wv] = s2;
    __syncthreads();
    if (t == 0) mv[0] = rsqrtf((red[0] + red[1] + red[2] + red[3]) / 512.f + 1e-5f);
    __syncthreads();
    const float rsc = mv[0];
    rms_out[(long)row * 512 + i0] = __float2bfloat16(v0 * rsc * rms_w[i0]);
    rms_out[(long)row * 512 + i1] = __float2bfloat16(v1 * rsc * rms_w[i1]);
}

// =====================================================================
// Causal depthwise conv (K=4) + bias + SiLU, 4 d per thread (float4).
// =====================================================================
__global__ void conv_silu_kernel(const float* __restrict__ xr, const float* __restrict__ w,
                                 const float* __restrict__ bias, float* __restrict__ xm,
                                 bf16* __restrict__ xmb)
{
    const int idx = blockIdx.x * 256 + threadIdx.x;   // cB*cL*cDI/4 threads
    const int d4 = idx & (cDI / 4 - 1);               // 0..255
    const int l  = (idx >> 8) & (cL - 1);
    const int b  = idx >> 18;
    const int d  = d4 * 4;
    float4 acc = *(const float4*)(bias + d);
    float w0a[4], w1a[4], w2a[4], w3a[4];
    *(float4*)w0a = *(const float4*)(w + (d + 0) * cKC);
    *(float4*)w1a = *(const float4*)(w + (d + 1) * cKC);
    *(float4*)w2a = *(const float4*)(w + (d + 2) * cKC);
    *(float4*)w3a = *(const float4*)(w + (d + 3) * cKC);
#pragma unroll
    for (int j = 0; j < cKC; j++) {
        const int ls = l + j - (cKC - 1);
        if (ls >= 0) {
            const float4 xv = *(const float4*)(xr + ((long)(b * cL + ls)) * (2 * cDI) + d);
            acc.x = fmaf(w0a[j], xv.x, acc.x);
            acc.y = fmaf(w1a[j], xv.y, acc.y);
            acc.z = fmaf(w2a[j], xv.z, acc.z);
            acc.w = fmaf(w3a[j], xv.w, acc.w);
        }
    }
    acc.x = acc.x / (1.f + __expf(-acc.x));
    acc.y = acc.y / (1.f + __expf(-acc.y));
    acc.z = acc.z / (1.f + __expf(-acc.z));
    acc.w = acc.w / (1.f + __expf(-acc.w));
    const long o = ((long)(b * cL + l)) * cDI + d;
    *(float4*)(xm + o) = acc;
    bf16 b0 = __float2bfloat16(acc.x), b1 = __float2bfloat16(acc.y);
    bf16 b2 = __float2bfloat16(acc.z), b3 = __float2bfloat16(acc.w);
    short4 pk = { *(short*)&b0, *(short*)&b1, *(short*)&b2, *(short*)&b3 };
    *(short4*)(xmb + o) = pk;
}

// =====================================================================
// Chunk-parallel selective scan; ONE thread per (b,ch,d), all 16 n-states
// in registers.  d stays in the fast thread dim (wave = 64 consecutive d
// -> coalesced dl/u/res/y; B/C rows wave-uniform -> L1 broadcast).
// Summary layout unchanged: ((b*NCH+ch)*DI+d)*DS + n.
// idx bits: d[9:0], ch[15:10], b[16]
// =====================================================================
__global__ __launch_bounds__(256)
void scan_phase1(const float* __restrict__ xm, const float* __restrict__ delta,
                 const float* __restrict__ xdbl, const float* __restrict__ Alog,
                 float* __restrict__ aprod_out, float* __restrict__ send_out)
{
    const int idx = blockIdx.x * 256 + threadIdx.x;   // cB*cNCH*cDI
    const int d  = idx & (cDI - 1);
    const int ch = (idx >> 10) & (cNCH - 1);
    const int b  = idx >> 16;
    float A[16], s[16], p[16];
#pragma unroll
    for (int g = 0; g < 4; g++) {
        const float4 v = *(const float4*)(Alog + d * cDS + 4 * g);
        A[4 * g + 0] = -__expf(v.x); A[4 * g + 1] = -__expf(v.y);
        A[4 * g + 2] = -__expf(v.z); A[4 * g + 3] = -__expf(v.w);
    }
#pragma unroll
    for (int n = 0; n < 16; n++) { s[n] = 0.f; p[n] = 1.f; }
    const int l0 = ch * cCHL;
    const float* dp = delta + (long)(b * cL + l0) * cDI + d;
    const float* up = xm    + (long)(b * cL + l0) * cDI + d;
    const float* xb = xdbl  + (long)(b * cL + l0) * 64 + cDTR;
#pragma unroll
    for (int t = 0; t < cCHL; t++) {
        const float dl = dp[(long)t * cDI];
        const float du = dl * up[(long)t * cDI];
#pragma unroll
        for (int g = 0; g < 4; g++) {
            const float4 Bv = *(const float4*)(xb + (long)t * 64 + 4 * g);
            float a;
            a = __expf(dl * A[4 * g + 0]); s[4 * g + 0] = fmaf(du, Bv.x, a * s[4 * g + 0]); p[4 * g + 0] *= a;
            a = __expf(dl * A[4 * g + 1]); s[4 * g + 1] = fmaf(du, Bv.y, a * s[4 * g + 1]); p[4 * g + 1] *= a;
            a = __expf(dl * A[4 * g + 2]); s[4 * g + 2] = fmaf(du, Bv.z, a * s[4 * g + 2]); p[4 * g + 2] *= a;
            a = __expf(dl * A[4 * g + 3]); s[4 * g + 3] = fmaf(du, Bv.w, a * s[4 * g + 3]); p[4 * g + 3] *= a;
        }
    }
    float* pa = aprod_out + (((long)(b * cNCH + ch) * cDI + d) * cDS);
    float* ps = send_out  + (((long)(b * cNCH + ch) * cDI + d) * cDS);
#pragma unroll
    for (int g = 0; g < 4; g++) {
        *(float4*)(pa + 4 * g) = make_float4(p[4 * g], p[4 * g + 1], p[4 * g + 2], p[4 * g + 3]);
        *(float4*)(ps + 4 * g) = make_float4(s[4 * g], s[4 * g + 1], s[4 * g + 2], s[4 * g + 3]);
    }
}

__global__ void scan_phase2(const float* __restrict__ aprod, const float* __restrict__ send,
                            float* __restrict__ sinit)
{
    const int j = blockIdx.x * 64 + threadIdx.x;    // cB*cDI*cDS, 64-thr blocks
    const int n = j & (cDS - 1);
    const int d = (j >> 4) & (cDI - 1);
    const int b = j >> 14;
    float s = 0.f;
#pragma unroll
    for (int c = 0; c < cNCH; c++) {
        const long off = (((long)(b * cNCH + c) * cDI + d) * cDS) + n;
        sinit[off] = s;
        s = aprod[off] * s + send[off];
    }
}

__global__ __launch_bounds__(256)
void scan_phase3(const float* __restrict__ xm, const float* __restrict__ delta,
                 const float* __restrict__ xdbl, const float* __restrict__ Alog,
                 const float* __restrict__ Dv, const float* __restrict__ xr,
                 const float* __restrict__ sinit, bf16* __restrict__ y)
{
    const int idx = blockIdx.x * 256 + threadIdx.x;   // cB*cNCH*cDI
    const int d  = idx & (cDI - 1);
    const int ch = (idx >> 10) & (cNCH - 1);
    const int b  = idx >> 16;
    float A[16], s[16];
#pragma unroll
    for (int g = 0; g < 4; g++) {
        const float4 v = *(const float4*)(Alog + d * cDS + 4 * g);
        A[4 * g + 0] = -__expf(v.x); A[4 * g + 1] = -__expf(v.y);
        A[4 * g + 2] = -__expf(v.z); A[4 * g + 3] = -__expf(v.w);
    }
    const float Dval = Dv[d];
    const float* si = sinit + (((long)(b * cNCH + ch) * cDI + d) * cDS);
#pragma unroll
    for (int g = 0; g < 4; g++) {
        const float4 v = *(const float4*)(si + 4 * g);
        s[4 * g + 0] = v.x; s[4 * g + 1] = v.y; s[4 * g + 2] = v.z; s[4 * g + 3] = v.w;
    }
    const int l0 = ch * cCHL;
    const float* dp = delta + (long)(b * cL + l0) * cDI + d;
    const float* up = xm    + (long)(b * cL + l0) * cDI + d;
    const float* xb = xdbl  + (long)(b * cL + l0) * 64 + cDTR;
    const float* rp = xr + (long)(b * cL + l0) * (2 * cDI) + cDI + d;
    bf16* yp = y + (long)(b * cL + l0) * cDI + d;
#pragma unroll
    for (int t = 0; t < cCHL; t++) {
        const float dl = dp[(long)t * cDI];
        const float u  = up[(long)t * cDI];
        const float du = dl * u;
        float c = 0.f;
#pragma unroll
        for (int g = 0; g < 4; g++) {
            const float4 Bv = *(const float4*)(xb + (long)t * 64 + 4 * g);
            const float4 Cv = *(const float4*)(xb + (long)t * 64 + cDS + 4 * g);
            float a;
            a = __expf(dl * A[4 * g + 0]); s[4 * g + 0] = fmaf(du, Bv.x, a * s[4 * g + 0]); c = fmaf(s[4 * g + 0], Cv.x, c);
            a = __expf(dl * A[4 * g + 1]); s[4 * g + 1] = fmaf(du, Bv.y, a * s[4 * g + 1]); c = fmaf(s[4 * g + 1], Cv.y, c);
            a = __expf(dl * A[4 * g + 2]); s[4 * g + 2] = fmaf(du, Bv.z, a * s[4 * g + 2]); c = fmaf(s[4 * g + 2], Cv.z, c);
            a = __expf(dl * A[4 * g + 3]); s[4 * g + 3] = fmaf(du, Bv.w, a * s[4 * g + 3]); c = fmaf(s[4 * g + 3], Cv.w, c);
        }
        const float res = rp[(long)t * 2 * cDI];
        const float sig = 1.f / (1.f + __expf(-res));
        yp[(long)t * cDI] = __float2bfloat16((c + u * Dval) * (res * sig));
    }
}

// =====================================================================
extern "C" void kernel_launch(void* const* d_in, const int* in_sizes, int n_in,
                              void* d_out, int out_size, void* d_ws, size_t ws_size,
                              hipStream_t stream)
{
    const float* x       = (const float*)d_in[0];
    const float* enc     = (const float*)d_in[1];
    const float* W_in    = (const float*)d_in[2];
    const float* b_in    = (const float*)d_in[3];
    const float* m_norm_w= (const float*)d_in[4];
    const float* m_in_w  = (const float*)d_in[5];
    const float* m_conv_w= (const float*)d_in[6];
    const float* m_conv_b= (const float*)d_in[7];
    const float* m_xproj = (const float*)d_in[8];
    const float* m_dt_w  = (const float*)d_in[9];
    const float* m_dt_b  = (const float*)d_in[10];
    const float* m_Alog  = (const float*)d_in[11];
    const float* m_D     = (const float*)d_in[12];
    const float* m_out_w = (const float*)d_in[13];
    const float* a_in_w  = (const float*)d_in[14];
    const float* a_in_b  = (const float*)d_in[15];
    const float* a_out_w = (const float*)d_in[16];
    const float* a_out_b = (const float*)d_in[17];
    const float* a_ln_w  = (const float*)d_in[18];
    const float* a_ln_b  = (const float*)d_in[19];
    const float* normf_w = (const float*)d_in[20];
    const float* W_out   = (const float*)d_in[21];
    float* out = (float*)d_out;

    float* ws = (float*)d_ws;
    long off = 0;
    auto allocf = [&](long n) { float* p = ws + off; off += n; return p; };

    const long M1 = 1 << 20;
    float* bufH    = allocf(M1);
    float* bufPre  = allocf(M1);         // also xproj split-K partials
    float* bufXR   = allocf(4 * M1);
    float* bufXM   = allocf(2 * M1);
    float* bufDelta= allocf(2 * M1);
    float* bufXDBL = allocf(M1 / 8);
    bf16* bufU    = (bf16*)allocf(M1 / 2);      // 2048x512 bf16 (rms output)
    bf16* bufHb   = (bf16*)allocf(M1 / 2);
    bf16* bufXMb  = (bf16*)allocf(M1);          // 2048x1024 bf16
    bf16* bufXDBLb= (bf16*)allocf(M1 / 16);
    bf16* bufY    = (bf16*)allocf(M1);          // 2048x1024 bf16
    bf16* bufQ    = (bf16*)allocf(M1 / 2);
    bf16* bufO    = (bf16*)allocf(M1 / 2);
    bf16* encb    = (bf16*)allocf(M1 / 2);
    bf16* w_in_b  = (bf16*)allocf(2 * M1);
    bf16* w_xp_b  = (bf16*)allocf(M1 / 8);
    bf16* w_dt_b  = (bf16*)allocf(M1 / 16);
    bf16* w_out_b = (bf16*)allocf(M1);
    bf16* w_ain_b = (bf16*)allocf(3 * M1 / 2);
    bf16* w_aout_b= (bf16*)allocf(M1 / 2);
    bf16* x_pad   = (bf16*)allocf(2048L * 96 / 2);
    bf16* w_inp_b = (bf16*)allocf(512L * 96 / 2);
    bf16* w_outf_b= (bf16*)allocf(80L * 512 / 2);
    float* bufAP  = allocf(2 * M1);
    float* bufSE  = allocf(2 * M1);
    float* bufSI  = allocf(2 * M1);
    bf16* bufKV4  = (bf16*)allocf(4 * M1);      // 4 layers x 2M bf16
    bf16* bufVT4  = (bf16*)allocf(2 * M1);      // 4 layers x 1M bf16
    float* bufOP  = allocf(4 * M1);             // flash partials [4][2048][512] f32
    float2* bufML = (float2*)allocf(M1 / 16);   // [4][2][4][1024] float2

    const int Mrows = cB * cL;   // 2048
    const int scanBlocks = (cB * cNCH * cDI) / 256;   // 512
    const long kvLS = (long)Mrows * 2 * cDM;
    const long vtLS = (long)cB * cDM * cLE;

    // ---- one-time conversions ----
    cvt_all_kernel<<<11688, 256, 0, stream>>>(
        enc, encb, m_in_w, w_in_b, m_xproj, w_xp_b, m_dt_w, w_dt_b,
        m_out_w, w_out_b, a_in_w, w_ain_b, a_out_w, w_aout_b, W_out, w_outf_b);
    cvt_pad_kernel<<<(Mrows * 96 + 255) / 256, 256, 0, stream>>>(x, x_pad, Mrows, cNM, 96);
    cvt_pad_kernel<<<(cDM * 96 + 255) / 256, 256, 0, stream>>>(W_in, w_inp_b, cDM, cNM, 96);

    // ---- all-layer K|V projection + V^T ----
    bgemm(0, 64, 128, encb, w_ain_b + (long)cDM * cDM, a_in_b + cDM, nullptr, nullptr, bufKV4,
          Mrows, 2 * cDM, cDM, cDM, cDM, 0, 2 * cDM, 0,
          cLAYERS, 1,
          0, 0,
          (long)3 * cDM * cDM, 0,
          0, 0, kvLS, 0,
          (long)3 * cDM,
          stream);
    {
        dim3 g(cLE / 32, cDM / 32, cLAYERS * cB);
        transpose_bf16_kernel<<<g, 256, 0, stream>>>(bufKV4, bufVT4, 2 * cDM, cDM, kvLS, vtLS);
    }

    // h = x @ W_in.T + b_in ; layer-0 rmsnorm -> bufU
    bgemm_plain(0, 64, 64, x_pad, w_inp_b, b_in, nullptr, bufH, nullptr,
                Mrows, cDM, 96, 96, 96, cDM, 0, 0, stream);
    rmsnorm_kernel<<<Mrows, 256, 0, stream>>>(bufH, m_norm_w, nullptr, bufU, cDM);

    for (int i = 0; i < cLAYERS; i++) {
        const bf16*  in_w   = w_in_b   + (long)i * 2 * cDI * cDM;
        const float* conv_w = m_conv_w + (long)i * cDI * cKC;
        const float* conv_b = m_conv_b + (long)i * cDI;
        const bf16*  xproj  = w_xp_b   + (long)i * 64 * cDI;
        const bf16*  dt_w   = w_dt_b   + (long)i * cDI * cDTR;
        const float* dt_b   = m_dt_b   + (long)i * cDI;
        const float* Alog   = m_Alog   + (long)i * cDI * cDS;
        const float* Dv     = m_D      + (long)i * cDI;
        const bf16*  out_w  = w_out_b  + (long)i * cDM * cDI;
        const bf16*  ain_w  = w_ain_b  + (long)i * 3 * cDM * cDM;
        const float* ain_b  = a_in_b   + (long)i * 3 * cDM;
        const bf16*  aout_w = w_aout_b + (long)i * cDM * cDM;
        const float* aout_b = a_out_b  + (long)i * cDM;
        const float* ln_w   = a_ln_w   + (long)i * cDM;
        const float* ln_b   = a_ln_b   + (long)i * cDM;
        const bf16*  kv_l   = bufKV4 + (long)i * kvLS;
        const bf16*  vt_l   = bufVT4 + (long)i * vtLS;
        const float* next_rms_w = (i + 1 < cLAYERS) ? (m_norm_w + (long)(i + 1) * cDM) : normf_w;

        // ---- mamba (bufU holds rmsnorm(h) bf16) ----
        bgemm_plain(0, 64, 128, bufU, in_w, nullptr, nullptr, bufXR, nullptr,
                    Mrows, 2 * cDI, cDM, cDM, cDM, 2 * cDI, 0, 0, stream);
        conv_silu_kernel<<<(cB * cL * cDI / 4) / 256, 256, 0, stream>>>(bufXR, conv_w, conv_b, bufXM, bufXMb);
        bgemm(0, 64, 64, bufXMb, xproj, nullptr, nullptr, bufPre, nullptr,
              Mrows, 64, cDI / 8, cDI, cDI, 64, 0, 0,
              8, 1, 128, 0, 128, 0, (long)Mrows * 64, 0, 0, 0, 0, stream);
        splitk_reduce_kernel<<<(Mrows * 64 / 4 + 255) / 256, 256, 0, stream>>>(
            bufPre, bufXDBL, bufXDBLb, Mrows * 64 / 4, Mrows * 64 / 4, 8);
        bgemm_plain(1, 64, 128, bufXDBLb, dt_w, dt_b, nullptr, bufDelta, nullptr,
                    Mrows, cDI, cDTR, 64, cDTR, cDI, 0, 0, stream);
        scan_phase1<<<scanBlocks, 256, 0, stream>>>(bufXM, bufDelta, bufXDBL, Alog, bufAP, bufSE);
        scan_phase2<<<(cB * cDI * cDS) / 64, 64, 0, stream>>>(bufAP, bufSE, bufSI);
        scan_phase3<<<scanBlocks, 256, 0, stream>>>(bufXM, bufDelta, bufXDBL, Alog, Dv, bufXR, bufSI, bufY);
        bgemm_plain(0, 64, 64, bufY, out_w, nullptr, bufH, bufH, bufHb,
                    Mrows, cDM, cDI, cDI, cDI, cDM, cDM, cDM, stream);

        // ---- cross attention: Q gemm -> split flash -> combine ----
        bgemm_plain(0, 64, 64, bufHb, ain_w, ain_b, nullptr, nullptr, bufQ,
                    Mrows, cDM, cDM, cDM, cDM, 0, cDM, 0, stream);
        {
            dim3 g(cL / 32, cB * cH, cSPL);
            flash_split_kernel<<<g, 128, 0, stream>>>(bufQ, kv_l, vt_l, bufOP, bufML,
                                                      0.08838834764831845f);
        }
        flash_combine_kernel<<<Mrows, 256, 0, stream>>>(bufOP, bufML, bufO);
        // pre = o @ aout_w.T + aout_b + h ; h = LN(pre) (+ fused next-RMS -> bufU)
        bgemm_plain(0, 64, 64, bufO, aout_w, aout_b, bufH, bufPre, nullptr,
                    Mrows, cDM, cDM, cDM, cDM, cDM, 0, cDM, stream);
        layernorm_kernel<<<Mrows, 256, 0, stream>>>(bufPre, ln_w, ln_b, bufH, bufHb,
                                                    next_rms_w, bufU);
    }

    // final: out = bufU(= rms(h, normf_w)) @ W_out.T
    bgemm_plain(0, 64, 64, bufU, w_outf_b, nullptr, nullptr, out, nullptr,
                Mrows, cNM, cDM, cDM, cDM, cNM, 0, 0, stream);
}